// Round 1
// baseline (1111.610 us; speedup 1.0000x reference)
//
#include <hip/hip_runtime.h>
#include <math.h>

// Problem constants
#define BB 4
#define HH 48
#define WW 48
#define DD 64
#define CH 46
#define CWp 46
#define CC (CH*CWp)      // 2116
#define KK 576           // 9*64
#define HWp (HH*WW)      // 2304

// Workspace layout (floats)
#define OFF_P1 ((size_t)0)
#define SZ_P1  ((size_t)BB*CC*KK)          // 4,875,264
#define OFF_P2 (OFF_P1 + SZ_P1)            // p2, reused as agg after GEMM2
#define SZ_P2  ((size_t)BB*HWp*KK)         // 5,308,416
#define OFF_S  (OFF_P2 + SZ_P2)
#define SZ_S   ((size_t)BB*HWp*CC)         // 19,501,056
#define OFF_BG (OFF_S + SZ_S)
#define SZ_BG  ((size_t)BB*HWp*DD)         // 589,824
#define OFF_K1 (OFF_BG + SZ_BG)
#define SZ_K1  ((size_t)BB*CC)             // 8,464
#define OFF_WW (OFF_K1 + SZ_K1)
#define SZ_WW  ((size_t)BB*HWp)            // 9,216

// ---------------- reductions ----------------
__device__ __forceinline__ float waveReduceSum(float x) {
#pragma unroll
    for (int o = 32; o > 0; o >>= 1) x += __shfl_down(x, o, 64);
    return x;
}

__device__ __forceinline__ float blockReduceSum(float x, float* sm) {
#pragma unroll
    for (int o = 32; o > 0; o >>= 1) x += __shfl_down(x, o, 64);
    int lane = threadIdx.x & 63, w = threadIdx.x >> 6;
    __syncthreads();
    if (lane == 0) sm[w] = x;
    __syncthreads();
    return sm[0] + sm[1] + sm[2] + sm[3];
}

__device__ __forceinline__ float blockReduceMax(float x, float* sm) {
#pragma unroll
    for (int o = 32; o > 0; o >>= 1) x = fmaxf(x, __shfl_down(x, o, 64));
    int lane = threadIdx.x & 63, w = threadIdx.x >> 6;
    __syncthreads();
    if (lane == 0) sm[w] = x;
    __syncthreads();
    return fmaxf(fmaxf(sm[0], sm[1]), fmaxf(sm[2], sm[3]));
}

// ---------------- prep kernels ----------------
// bg = g * mask (mask broadcast over channel)
__global__ __launch_bounds__(256) void build_bg(const float* __restrict__ g,
                                                const float* __restrict__ mask,
                                                float* __restrict__ bg) {
    size_t i = (size_t)blockIdx.x * 256 + threadIdx.x;
    bg[i] = g[i] * mask[i >> 6];
}

// p2[b,(y,x),(dy,dx,c)] = pad(g)[b,y+dy-1,x+dx-1,c]; wwd[b,(y,x)] = sum(p2^2)
__global__ __launch_bounds__(64) void build_p2(const float* __restrict__ g,
                                               float* __restrict__ p2,
                                               float* __restrict__ wwd) {
    int pix = blockIdx.x;               // b*HW + y*W + x
    int b = pix / HWp, yx = pix % HWp;
    int y = yx / WW, x = yx % WW;
    int c = threadIdx.x;
    const float* gb = g + (size_t)b * HWp * DD;
    float* dst = p2 + (size_t)pix * KK;
    float ss = 0.f;
#pragma unroll
    for (int dy = 0; dy < 3; dy++) {
#pragma unroll
        for (int dx = 0; dx < 3; dx++) {
            int yy = y + dy - 1, xx = x + dx - 1;
            float v = (yy >= 0 && yy < HH && xx >= 0 && xx < WW)
                          ? gb[((size_t)yy * WW + xx) * DD + c] : 0.f;
            dst[(dy * 3 + dx) * DD + c] = v;
            ss += v * v;
        }
    }
    ss = waveReduceSum(ss);
    if (c == 0) wwd[pix] = ss;
}

// p1[b,j,(dy,dx,c)] = bg[b,jy+dy,jx+dx,c]; k1d[b,j] = sum(p1^2)
__global__ __launch_bounds__(64) void build_p1(const float* __restrict__ bg,
                                               float* __restrict__ p1,
                                               float* __restrict__ k1d) {
    int j = blockIdx.x;                 // b*C + jj
    int b = j / CC, jj = j % CC;
    int jy = jj / CWp, jx = jj % CWp;
    int c = threadIdx.x;
    const float* bgb = bg + (size_t)b * HWp * DD;
    float* dst = p1 + (size_t)j * KK;
    float ss = 0.f;
#pragma unroll
    for (int dy = 0; dy < 3; dy++) {
#pragma unroll
        for (int dx = 0; dx < 3; dx++) {
            float v = bgb[((size_t)(jy + dy) * WW + (jx + dx)) * DD + c];
            dst[(dy * 3 + dx) * DD + c] = v;
            ss += v * v;
        }
    }
    ss = waveReduceSum(ss);
    if (c == 0) k1d[j] = ss;
}

// ---------------- GEMM1: S = DS1 = k1d + wwd - 2 * (p2 @ p1^T) ----------------
// A = p2 [2304,576], Bt = p1 [2116,576], out [2304,2116]
__global__ __launch_bounds__(256) void gemm1_nt_ds1(const float* __restrict__ P2,
                                                    const float* __restrict__ P1,
                                                    const float* __restrict__ k1d,
                                                    const float* __restrict__ wwd,
                                                    float* __restrict__ S) {
    int b = blockIdx.z;
    const float* A = P2 + (size_t)b * HWp * KK;
    const float* Bt = P1 + (size_t)b * CC * KK;
    float* Cp = S + (size_t)b * HWp * CC;
    int m0 = blockIdx.y * 64, n0 = blockIdx.x * 64;

    __shared__ float As[16][68];
    __shared__ float Bs[16][68];
    int tid = threadIdx.x;
    int tx = tid % 16, ty = tid / 16;
    int lk = tid % 16, lr = tid / 16;
    float acc[4][4] = {};

    for (int k0 = 0; k0 < KK; k0 += 16) {
#pragma unroll
        for (int i = 0; i < 4; i++) {
            int m = m0 + lr + i * 16;
            As[lk][lr + i * 16] = A[(size_t)m * KK + k0 + lk];
        }
#pragma unroll
        for (int i = 0; i < 4; i++) {
            int n = n0 + lr + i * 16;
            Bs[lk][lr + i * 16] = (n < CC) ? Bt[(size_t)n * KK + k0 + lk] : 0.f;
        }
        __syncthreads();
#pragma unroll
        for (int kk = 0; kk < 16; kk++) {
            float a[4], bv[4];
#pragma unroll
            for (int i = 0; i < 4; i++) a[i] = As[kk][ty * 4 + i];
#pragma unroll
            for (int j = 0; j < 4; j++) bv[j] = Bs[kk][tx * 4 + j];
#pragma unroll
            for (int i = 0; i < 4; i++)
#pragma unroll
                for (int j = 0; j < 4; j++) acc[i][j] += a[i] * bv[j];
        }
        __syncthreads();
    }
#pragma unroll
    for (int i = 0; i < 4; i++) {
        int m = m0 + ty * 4 + i;
        float wv = wwd[b * HWp + m];
#pragma unroll
        for (int j = 0; j < 4; j++) {
            int n = n0 + tx * 4 + j;
            if (n < CC)
                Cp[(size_t)m * CC + n] = k1d[b * CC + n] + wv - 2.f * acc[i][j];
        }
    }
}

// ---------------- row-wise standardize + tanh + softmax (in place) ----------------
__global__ __launch_bounds__(256) void rowsoft(float* __restrict__ S) {
    __shared__ float sm[4];
    size_t row = blockIdx.x;
    float* p = S + row * (size_t)CC;
    int tid = threadIdx.x;
    float v[9];
#pragma unroll
    for (int i = 0; i < 9; i++) {
        int idx = tid + i * 256;
        v[i] = (idx < CC) ? p[idx] : 0.f;
    }
    float s = 0.f;
#pragma unroll
    for (int i = 0; i < 9; i++) { int idx = tid + i * 256; if (idx < CC) s += v[i]; }
    s = blockReduceSum(s, sm);
    float mu = s / (float)CC;
    float vs = 0.f;
#pragma unroll
    for (int i = 0; i < 9; i++) {
        int idx = tid + i * 256;
        if (idx < CC) { float d = v[i] - mu; vs += d * d; }
    }
    vs = blockReduceSum(vs, sm);
    float inv_sd = 1.f / sqrtf(vs / (float)CC);
    float mx = -1e30f;
#pragma unroll
    for (int i = 0; i < 9; i++) {
        int idx = tid + i * 256;
        if (idx < CC) {
            v[i] = -50.f * tanhf((v[i] - mu) * inv_sd);
            mx = fmaxf(mx, v[i]);
        }
    }
    mx = blockReduceMax(mx, sm);
    float es = 0.f;
#pragma unroll
    for (int i = 0; i < 9; i++) {
        int idx = tid + i * 256;
        if (idx < CC) { v[i] = expf(v[i] - mx); es += v[i]; }
    }
    es = blockReduceSum(es, sm);
    float invz = 1.f / es;
#pragma unroll
    for (int i = 0; i < 9; i++) {
        int idx = tid + i * 256;
        if (idx < CC) p[idx] = v[i] * invz;
    }
}

// ---------------- GEMM2: agg = CA @ p1 : [2304,2116] x [2116,576] ----------------
__global__ __launch_bounds__(256) void gemm2_nn(const float* __restrict__ CA,
                                                const float* __restrict__ P1,
                                                float* __restrict__ AGG) {
    int b = blockIdx.z;
    const float* A = CA + (size_t)b * HWp * CC;
    const float* Bm = P1 + (size_t)b * CC * KK;
    float* Cp = AGG + (size_t)b * HWp * KK;
    int m0 = blockIdx.y * 64, n0 = blockIdx.x * 64;

    __shared__ float As[16][68];
    __shared__ float Bs[16][68];
    int tid = threadIdx.x;
    int tx = tid % 16, ty = tid / 16;
    int lk = tid % 16, lr = tid / 16;   // A-tile loads
    int bn = tid % 64, bk = tid / 64;   // B-tile loads
    float acc[4][4] = {};

    for (int k0 = 0; k0 < CC; k0 += 16) {
#pragma unroll
        for (int i = 0; i < 4; i++) {
            int m = m0 + lr + i * 16;
            int k = k0 + lk;
            As[lk][lr + i * 16] = (k < CC) ? A[(size_t)m * CC + k] : 0.f;
        }
#pragma unroll
        for (int i = 0; i < 4; i++) {
            int k = k0 + bk + i * 4;
            Bs[bk + i * 4][bn] = (k < CC) ? Bm[(size_t)k * KK + n0 + bn] : 0.f;
        }
        __syncthreads();
#pragma unroll
        for (int kk = 0; kk < 16; kk++) {
            float a[4], bv[4];
#pragma unroll
            for (int i = 0; i < 4; i++) a[i] = As[kk][ty * 4 + i];
#pragma unroll
            for (int j = 0; j < 4; j++) bv[j] = Bs[kk][tx * 4 + j];
#pragma unroll
            for (int i = 0; i < 4; i++)
#pragma unroll
                for (int j = 0; j < 4; j++) acc[i][j] += a[i] * bv[j];
        }
        __syncthreads();
    }
#pragma unroll
    for (int i = 0; i < 4; i++) {
        int m = m0 + ty * 4 + i;
#pragma unroll
        for (int j = 0; j < 4; j++) {
            Cp[(size_t)m * KK + n0 + tx * 4 + j] = acc[i][j];
        }
    }
}

// ---------------- final: acl shift-combine + ACL + concat + W2 matmul + ELU ----------------
__global__ __launch_bounds__(64) void final_k(const float* __restrict__ g,
                                              const float* __restrict__ mask,
                                              const float* __restrict__ bg,
                                              const float* __restrict__ agg,
                                              const float* __restrict__ W2,
                                              const float* __restrict__ b2,
                                              float* __restrict__ out) {
    int pix = blockIdx.x;               // b*HW + y*W + x
    int b = pix / HWp, yx = pix % HWp;
    int y = yx / WW, x = yx % WW;
    int d = threadIdx.x;

    __shared__ float con1[128];
    float acl = 0.f;
#pragma unroll
    for (int dy = 0; dy < 3; dy++) {
#pragma unroll
        for (int dx = 0; dx < 3; dx++) {
            int yy = y + 1 - dy, xx = x + 1 - dx;
            if (yy >= 0 && yy < HH && xx >= 0 && xx < WW) {
                acl += agg[((size_t)(b * HWp + yy * WW + xx)) * KK + (dy * 3 + dx) * DD + d];
            }
        }
    }
    float m = mask[pix];
    float gv = g[(size_t)pix * DD + d];
    float bgv = bg[(size_t)pix * DD + d];
    float ACL = bgv + (acl / 9.f) * (1.f - m);
    con1[d] = gv;
    con1[64 + d] = ACL;
    __syncthreads();
    float accv = b2[d];
#pragma unroll 8
    for (int k = 0; k < 128; k++) accv = fmaf(con1[k], W2[k * 64 + d], accv);
    out[(size_t)pix * DD + d] = accv > 0.f ? accv : expm1f(accv);
}

extern "C" void kernel_launch(void* const* d_in, const int* in_sizes, int n_in,
                              void* d_out, int out_size, void* d_ws, size_t ws_size,
                              hipStream_t stream) {
    const float* g    = (const float*)d_in[0];
    const float* mask = (const float*)d_in[1];
    const float* W2   = (const float*)d_in[2];
    const float* b2   = (const float*)d_in[3];
    float* out = (float*)d_out;
    float* ws = (float*)d_ws;

    float* p1  = ws + OFF_P1;
    float* p2  = ws + OFF_P2;   // reused as agg by gemm2
    float* S   = ws + OFF_S;
    float* bg  = ws + OFF_BG;
    float* k1d = ws + OFF_K1;
    float* wwd = ws + OFF_WW;

    build_bg<<<(BB * HWp * DD) / 256, 256, 0, stream>>>(g, mask, bg);
    build_p2<<<BB * HWp, 64, 0, stream>>>(g, p2, wwd);
    build_p1<<<BB * CC, 64, 0, stream>>>(bg, p1, k1d);
    gemm1_nt_ds1<<<dim3(34, 36, BB), 256, 0, stream>>>(p2, p1, k1d, wwd, S);
    rowsoft<<<BB * HWp, 256, 0, stream>>>(S);
    gemm2_nn<<<dim3(9, 36, BB), 256, 0, stream>>>(S, p1, p2);
    final_k<<<BB * HWp, 64, 0, stream>>>(g, mask, bg, p2, W2, b2, out);
}

// Round 2
// 248.663 us; speedup vs baseline: 4.4703x; 4.4703x over previous
//
#include <hip/hip_runtime.h>
#include <hip/hip_fp16.h>
#include <math.h>

// Problem constants
#define BB 4
#define HH 48
#define WW 48
#define DD 64
#define CH 46
#define CWp 46
#define CC (CH*CWp)      // 2116
#define KK 576           // 9*64
#define HWp (HH*WW)      // 2304
#define KPAD 2144        // 67*32, padded K for GEMM2 / row stride of S & CA

typedef __attribute__((ext_vector_type(8))) short short8;
typedef __attribute__((ext_vector_type(4))) float float4v;

// ---------- workspace layout (byte offsets, all 16B-aligned) ----------
#define OFFB_BG   ((size_t)0)                               // fp32 [B][HW][64]       2,359,296 B
#define OFFB_P1H  ((size_t)2359296)                         // bf16 [B][CC][576]      9,750,528 B
#define OFFB_P2H  ((size_t)12109824)                        // bf16 [B][HW][576]     10,616,832 B
#define OFFB_P1T  ((size_t)22726656)                        // bf16 [B][576][KPAD]    9,879,552 B
#define OFFB_K1D  ((size_t)32606208)                        // fp32 [B][CC]              33,856 B
#define OFFB_S    ((size_t)32640064)                        // fp16 [B][HW][KPAD] (reused as bf16 CA) 39,518,208 B
#define OFFB_AGG  ((size_t)72158272)                        // fp32 [B][HW][576]     21,233,664 B

// ---------- helpers ----------
__device__ __forceinline__ ushort f2bf(float x) {
    unsigned u = __float_as_uint(x);
    return (ushort)((u + 0x7FFFu + ((u >> 16) & 1u)) >> 16);
}

__device__ __forceinline__ float waveReduceSum(float x) {
#pragma unroll
    for (int o = 32; o > 0; o >>= 1) x += __shfl_down(x, o, 64);
    return x;
}

__device__ __forceinline__ float blockReduceSum(float x, float* sm) {
#pragma unroll
    for (int o = 32; o > 0; o >>= 1) x += __shfl_down(x, o, 64);
    int lane = threadIdx.x & 63, w = threadIdx.x >> 6;
    __syncthreads();
    if (lane == 0) sm[w] = x;
    __syncthreads();
    return sm[0] + sm[1] + sm[2] + sm[3];
}

__device__ __forceinline__ float blockReduceMax(float x, float* sm) {
#pragma unroll
    for (int o = 32; o > 0; o >>= 1) x = fmaxf(x, __shfl_down(x, o, 64));
    int lane = threadIdx.x & 63, w = threadIdx.x >> 6;
    __syncthreads();
    if (lane == 0) sm[w] = x;
    __syncthreads();
    return fmaxf(fmaxf(sm[0], sm[1]), fmaxf(sm[2], sm[3]));
}

// ---------- prep kernels ----------
__global__ __launch_bounds__(256) void build_bg(const float* __restrict__ g,
                                                const float* __restrict__ mask,
                                                float* __restrict__ bg) {
    size_t i = (size_t)blockIdx.x * 256 + threadIdx.x;
    bg[i] = g[i] * mask[i >> 6];
}

// p2h[b,(y,x),(dy,dx,c)] = bf16(pad(g)[b,y+dy-1,x+dx-1,c])
__global__ __launch_bounds__(64) void build_p2(const float* __restrict__ g,
                                               ushort* __restrict__ p2h) {
    int pix = blockIdx.x;
    int b = pix / HWp, yx = pix % HWp;
    int y = yx / WW, x = yx % WW;
    int c = threadIdx.x;
    const float* gb = g + (size_t)b * HWp * DD;
    ushort* dst = p2h + (size_t)pix * KK;
#pragma unroll
    for (int dy = 0; dy < 3; dy++) {
#pragma unroll
        for (int dx = 0; dx < 3; dx++) {
            int yy = y + dy - 1, xx = x + dx - 1;
            float v = (yy >= 0 && yy < HH && xx >= 0 && xx < WW)
                          ? gb[((size_t)yy * WW + xx) * DD + c] : 0.f;
            dst[(dy * 3 + dx) * DD + c] = f2bf(v);
        }
    }
}

// p1h[b,j,(dy,dx,c)] = bf16(bg[b,jy+dy,jx+dx,c]); k1d = fp32 sum of squares
__global__ __launch_bounds__(64) void build_p1(const float* __restrict__ bg,
                                               ushort* __restrict__ p1h,
                                               float* __restrict__ k1d) {
    int j = blockIdx.x;
    int b = j / CC, jj = j % CC;
    int jy = jj / CWp, jx = jj % CWp;
    int c = threadIdx.x;
    const float* bgb = bg + (size_t)b * HWp * DD;
    ushort* dst = p1h + (size_t)j * KK;
    float ss = 0.f;
#pragma unroll
    for (int dy = 0; dy < 3; dy++) {
#pragma unroll
        for (int dx = 0; dx < 3; dx++) {
            float v = bgb[((size_t)(jy + dy) * WW + (jx + dx)) * DD + c];
            dst[(dy * 3 + dx) * DD + c] = f2bf(v);
            ss += v * v;
        }
    }
    ss = waveReduceSum(ss);
    if (c == 0) k1d[j] = ss;
}

// p1t[b, c(576), j(KPAD)] = p1h[b, j, c], zero-filled for j >= CC
__global__ __launch_bounds__(256) void transpose_p1(const ushort* __restrict__ p1h,
                                                    ushort* __restrict__ p1t) {
    __shared__ ushort T[64 * 65];
    int b = blockIdx.z;
    int j0 = blockIdx.x * 64;   // 34 tiles over CC
    int c0 = blockIdx.y * 64;   // 9 tiles over 576
    const ushort* src = p1h + (size_t)b * CC * KK;
    ushort* dst = p1t + (size_t)b * KK * KPAD;
    int t = threadIdx.x;
#pragma unroll
    for (int pass = 0; pass < 2; pass++) {
        int v = t + pass * 256;
        int r = v >> 3, c8 = (v & 7) * 8;
        int j = j0 + r;
        uint4 d = make_uint4(0, 0, 0, 0);
        if (j < CC) d = *(const uint4*)(src + (size_t)j * KK + c0 + c8);
        ushort tmp[8];
        *(uint4*)tmp = d;
#pragma unroll
        for (int u = 0; u < 8; u++) T[r * 65 + c8 + u] = tmp[u];
    }
    __syncthreads();
#pragma unroll
    for (int pass = 0; pass < 2; pass++) {
        int v = t + pass * 256;
        int cr = v >> 3, j8 = (v & 7) * 8;
        int outj = j0 + j8;
        if (outj + 8 <= KPAD) {
            ushort tmp[8];
#pragma unroll
            for (int u = 0; u < 8; u++) tmp[u] = T[(j8 + u) * 65 + cr];
            *(uint4*)(dst + (size_t)(c0 + cr) * KPAD + outj) = *(uint4*)tmp;
        }
    }
}

// ---------- MFMA GEMM (NT): C[m][n] = sum_k A[m][k] * Bt[n][k] ----------
// EPI 0: store fp16 raw acc to C (ldc=KPAD), bound n<Nbound
// EPI 1: store fp32 acc to C (ldc=Nbound)
template <int EPI>
__global__ __launch_bounds__(256) void gemm_nt(const ushort* __restrict__ A,
                                               const ushort* __restrict__ Bt,
                                               void* __restrict__ Cout,
                                               int K, int lda, int ldb,
                                               int Nbound, int ldc,
                                               size_t strideA, size_t strideB, size_t strideC) {
    __shared__ ushort As[128 * 40];
    __shared__ ushort Bs[128 * 40];
    int b = blockIdx.z;
    const ushort* Ab = A + (size_t)b * strideA;
    const ushort* Bb = Bt + (size_t)b * strideB;
    int m0 = blockIdx.y * 128, n0 = blockIdx.x * 128;
    int tid = threadIdx.x;
    int lane = tid & 63, wid = tid >> 6;
    int quad = lane >> 4, l15 = lane & 15;
    int wm = (wid >> 1) * 64, wn = (wid & 1) * 64;

    float4v acc[4][4];
#pragma unroll
    for (int i = 0; i < 4; i++)
#pragma unroll
        for (int j = 0; j < 4; j++) acc[i][j] = (float4v){0.f, 0.f, 0.f, 0.f};

    int r0 = tid >> 2, c0 = (tid & 3) * 8;          // staging slot 0
    int r1 = (tid + 256) >> 2, c1 = (tid & 3) * 8;  // staging slot 1 (rows 64..127)

    for (int k0 = 0; k0 < K; k0 += 32) {
        // stage A (no m bounds: M=2304 divisible by 128)
        uint4 da0 = *(const uint4*)(Ab + (size_t)(m0 + r0) * lda + k0 + c0);
        uint4 da1 = *(const uint4*)(Ab + (size_t)(m0 + r1) * lda + k0 + c1);
        // stage B with n bound (zero-fill)
        uint4 db0 = make_uint4(0, 0, 0, 0), db1 = make_uint4(0, 0, 0, 0);
        if (n0 + r0 < Nbound) db0 = *(const uint4*)(Bb + (size_t)(n0 + r0) * ldb + k0 + c0);
        if (n0 + r1 < Nbound) db1 = *(const uint4*)(Bb + (size_t)(n0 + r1) * ldb + k0 + c1);
        *(uint4*)&As[r0 * 40 + c0] = da0;
        *(uint4*)&As[r1 * 40 + c1] = da1;
        *(uint4*)&Bs[r0 * 40 + c0] = db0;
        *(uint4*)&Bs[r1 * 40 + c1] = db1;
        __syncthreads();

        short8 af[4], bf[4];
#pragma unroll
        for (int i = 0; i < 4; i++)
            af[i] = *(const short8*)&As[(wm + i * 16 + l15) * 40 + quad * 8];
#pragma unroll
        for (int j = 0; j < 4; j++)
            bf[j] = *(const short8*)&Bs[(wn + j * 16 + l15) * 40 + quad * 8];
#pragma unroll
        for (int i = 0; i < 4; i++)
#pragma unroll
            for (int j = 0; j < 4; j++)
                acc[i][j] = __builtin_amdgcn_mfma_f32_16x16x32_bf16(af[i], bf[j], acc[i][j], 0, 0, 0);
        __syncthreads();
    }

    // epilogue: D mapping col = lane&15, row = quad*4 + reg
#pragma unroll
    for (int i = 0; i < 4; i++) {
#pragma unroll
        for (int j = 0; j < 4; j++) {
            int n = n0 + wn + j * 16 + l15;
            if (n < Nbound) {
#pragma unroll
                for (int r = 0; r < 4; r++) {
                    int m = m0 + wm + i * 16 + quad * 4 + r;
                    float val = acc[i][j][r];
                    if (EPI == 0) {
                        __half* C = (__half*)Cout + (size_t)b * strideC;
                        C[(size_t)m * ldc + n] = __float2half(val);
                    } else {
                        float* C = (float*)Cout + (size_t)b * strideC;
                        C[(size_t)m * ldc + n] = val;
                    }
                }
            }
        }
    }
}

// ---------- row-wise: t = k1d[n]-2*CS; standardize; -tanh; softmax; write bf16 CA in place ----------
__global__ __launch_bounds__(256) void rowsoft(void* __restrict__ Sbase,
                                               const float* __restrict__ k1d) {
    __shared__ float sm[4];
    size_t row = blockIdx.x;            // b*HW + pixel
    int b = (int)(row / HWp);
    const __half* p = (const __half*)Sbase + row * KPAD;
    ushort* wout = (ushort*)Sbase + row * KPAD;
    const float* k1 = k1d + (size_t)b * CC;
    int tid = threadIdx.x;
    float v[9];
#pragma unroll
    for (int i = 0; i < 9; i++) {
        int idx = tid + i * 256;
        v[i] = (idx < CC) ? (k1[idx] - 2.f * __half2float(p[idx])) : 0.f;
    }
    float s = 0.f;
#pragma unroll
    for (int i = 0; i < 9; i++) { int idx = tid + i * 256; if (idx < CC) s += v[i]; }
    s = blockReduceSum(s, sm);
    float mu = s / (float)CC;
    float vs = 0.f;
#pragma unroll
    for (int i = 0; i < 9; i++) {
        int idx = tid + i * 256;
        if (idx < CC) { float d = v[i] - mu; vs += d * d; }
    }
    vs = blockReduceSum(vs, sm);
    float inv_sd = 1.f / sqrtf(vs / (float)CC);
    float mx = -1e30f;
#pragma unroll
    for (int i = 0; i < 9; i++) {
        int idx = tid + i * 256;
        if (idx < CC) {
            v[i] = -50.f * tanhf((v[i] - mu) * inv_sd);
            mx = fmaxf(mx, v[i]);
        }
    }
    mx = blockReduceMax(mx, sm);
    float es = 0.f;
#pragma unroll
    for (int i = 0; i < 9; i++) {
        int idx = tid + i * 256;
        if (idx < CC) { v[i] = expf(v[i] - mx); es += v[i]; }
    }
    es = blockReduceSum(es, sm);
    float invz = 1.f / es;
#pragma unroll
    for (int i = 0; i < 9; i++) {
        int idx = tid + i * 256;
        if (idx < KPAD) wout[idx] = (idx < CC) ? f2bf(v[i] * invz) : (ushort)0;
    }
}

// ---------- final: acl shift-combine + ACL + concat + W2 matmul + ELU ----------
__global__ __launch_bounds__(64) void final_k(const float* __restrict__ g,
                                              const float* __restrict__ mask,
                                              const float* __restrict__ bg,
                                              const float* __restrict__ agg,
                                              const float* __restrict__ W2,
                                              const float* __restrict__ b2,
                                              float* __restrict__ out) {
    int pix = blockIdx.x;
    int b = pix / HWp, yx = pix % HWp;
    int y = yx / WW, x = yx % WW;
    int d = threadIdx.x;

    __shared__ float con1[128];
    float acl = 0.f;
#pragma unroll
    for (int dy = 0; dy < 3; dy++) {
#pragma unroll
        for (int dx = 0; dx < 3; dx++) {
            int yy = y + 1 - dy, xx = x + 1 - dx;
            if (yy >= 0 && yy < HH && xx >= 0 && xx < WW) {
                acl += agg[((size_t)(b * HWp + yy * WW + xx)) * KK + (dy * 3 + dx) * DD + d];
            }
        }
    }
    float m = mask[pix];
    float gv = g[(size_t)pix * DD + d];
    float bgv = bg[(size_t)pix * DD + d];
    float ACL = bgv + (acl / 9.f) * (1.f - m);
    con1[d] = gv;
    con1[64 + d] = ACL;
    __syncthreads();
    float accv = b2[d];
#pragma unroll 8
    for (int k = 0; k < 128; k++) accv = fmaf(con1[k], W2[k * 64 + d], accv);
    out[(size_t)pix * DD + d] = accv > 0.f ? accv : expm1f(accv);
}

extern "C" void kernel_launch(void* const* d_in, const int* in_sizes, int n_in,
                              void* d_out, int out_size, void* d_ws, size_t ws_size,
                              hipStream_t stream) {
    const float* g    = (const float*)d_in[0];
    const float* mask = (const float*)d_in[1];
    const float* W2   = (const float*)d_in[2];
    const float* b2   = (const float*)d_in[3];
    float* out = (float*)d_out;
    char* ws = (char*)d_ws;

    float*  bg  = (float*) (ws + OFFB_BG);
    ushort* p1h = (ushort*)(ws + OFFB_P1H);
    ushort* p2h = (ushort*)(ws + OFFB_P2H);
    ushort* p1t = (ushort*)(ws + OFFB_P1T);
    float*  k1d = (float*) (ws + OFFB_K1D);
    void*   S   = (void*)  (ws + OFFB_S);     // fp16 CS, then bf16 CA in place
    float*  agg = (float*) (ws + OFFB_AGG);

    build_bg<<<(BB * HWp * DD) / 256, 256, 0, stream>>>(g, mask, bg);
    build_p2<<<BB * HWp, 64, 0, stream>>>(g, p2h);
    build_p1<<<BB * CC, 64, 0, stream>>>(bg, p1h, k1d);
    transpose_p1<<<dim3(34, 9, BB), 256, 0, stream>>>(p1h, p1t);

    // GEMM1: CS = p2h @ p1h^T  -> S fp16 [HW][KPAD]
    gemm_nt<0><<<dim3(17, 18, BB), 256, 0, stream>>>(
        p2h, p1h, S, KK, KK, KK, CC, KPAD,
        (size_t)HWp * KK, (size_t)CC * KK, (size_t)HWp * KPAD);

    rowsoft<<<BB * HWp, 256, 0, stream>>>(S, k1d);

    // GEMM2: agg = CA @ p1t^T  (CA bf16 [HW][KPAD], p1t [576][KPAD]) -> agg fp32
    gemm_nt<1><<<dim3(5, 18, BB), 256, 0, stream>>>(
        (const ushort*)S, p1t, agg, KPAD, KPAD, KPAD, KK, KK,
        (size_t)HWp * KPAD, (size_t)KK * KPAD, (size_t)HWp * KK);

    final_k<<<BB * HWp, 64, 0, stream>>>(g, mask, bg, agg, W2, b2, out);
}

// Round 3
// 218.860 us; speedup vs baseline: 5.0791x; 1.1362x over previous
//
#include <hip/hip_runtime.h>
#include <hip/hip_fp16.h>
#include <math.h>

// Problem constants
#define BB 4
#define HH 48
#define WW 48
#define DD 64
#define CH 46
#define CWp 46
#define CC (CH*CWp)      // 2116
#define KK 576           // 9*64
#define HWp (HH*WW)      // 2304
#define KPAD 2144        // 67*32, padded K for GEMM2 / row stride of S & CA
#define KSPLIT0 1088     // 34*32
// chunk1 = [1088, 2144) = 33 iters

typedef __attribute__((ext_vector_type(8))) short short8;
typedef __attribute__((ext_vector_type(4))) float float4v;

// ---------- workspace layout (byte offsets, all 16B-aligned) ----------
#define OFFB_P1H  ((size_t)0)              // bf16 [B][CC][576]      9,750,528 B
#define OFFB_P2H  ((size_t)9750528)        // bf16 [B][HW][576]     10,616,832 B
#define OFFB_P1T  ((size_t)20367360)       // bf16 [B][576][KPAD]    9,879,552 B
#define OFFB_K1D  ((size_t)30246912)       // fp32 [B][CC]              33,856 B
#define OFFB_S    ((size_t)30280768)       // fp16 CS -> bf16 CA [B][HW][KPAD] 39,518,208 B
#define OFFB_AGG0 ((size_t)69798976)       // fp32 [B][HW][576]     21,233,664 B
#define OFFB_AGG1 ((size_t)91032640)       // fp32 [B][HW][576]     21,233,664 B
// total 112,266,304 B

// ---------- helpers ----------
__device__ __forceinline__ ushort f2bf(float x) {
    unsigned u = __float_as_uint(x);
    return (ushort)((u + 0x7FFFu + ((u >> 16) & 1u)) >> 16);
}

__device__ __forceinline__ float waveReduceSum(float x) {
#pragma unroll
    for (int o = 32; o > 0; o >>= 1) x += __shfl_down(x, o, 64);
    return x;
}

__device__ __forceinline__ float blockReduceSum(float x, float* sm) {
#pragma unroll
    for (int o = 32; o > 0; o >>= 1) x += __shfl_down(x, o, 64);
    int lane = threadIdx.x & 63, w = threadIdx.x >> 6;
    __syncthreads();
    if (lane == 0) sm[w] = x;
    __syncthreads();
    return sm[0] + sm[1] + sm[2] + sm[3];
}

// fast tanh via hardware exp: tanh(z) = 1 - 2/(e^{2z}+1)
__device__ __forceinline__ float fast_tanh(float z) {
    float e = __expf(2.f * z);
    return 1.f - 2.f / (e + 1.f);
}

// ---------- prep kernels (256 thr = 4 pixels/block, one wave each) ----------
// p2h[b,(y,x),(dy,dx,c)] = bf16(pad(g)[b,y+dy-1,x+dx-1,c])
__global__ __launch_bounds__(256) void build_p2(const float* __restrict__ g,
                                                ushort* __restrict__ p2h) {
    int pix = blockIdx.x * 4 + (threadIdx.x >> 6);
    int b = pix / HWp, yx = pix % HWp;
    int y = yx / WW, x = yx % WW;
    int c = threadIdx.x & 63;
    const float* gb = g + (size_t)b * HWp * DD;
    ushort* dst = p2h + (size_t)pix * KK;
#pragma unroll
    for (int dy = 0; dy < 3; dy++) {
#pragma unroll
        for (int dx = 0; dx < 3; dx++) {
            int yy = y + dy - 1, xx = x + dx - 1;
            float v = (yy >= 0 && yy < HH && xx >= 0 && xx < WW)
                          ? gb[((size_t)yy * WW + xx) * DD + c] : 0.f;
            dst[(dy * 3 + dx) * DD + c] = f2bf(v);
        }
    }
}

// p1h[b,j,(dy,dx,c)] = bf16(g*mask at [jy+dy, jx+dx]); k1d = fp32 sum of squares
__global__ __launch_bounds__(256) void build_p1(const float* __restrict__ g,
                                                const float* __restrict__ mask,
                                                ushort* __restrict__ p1h,
                                                float* __restrict__ k1d) {
    int j = blockIdx.x * 4 + (threadIdx.x >> 6);
    int b = j / CC, jj = j % CC;
    int jy = jj / CWp, jx = jj % CWp;
    int c = threadIdx.x & 63;
    const float* gb = g + (size_t)b * HWp * DD;
    const float* mb = mask + (size_t)b * HWp;
    ushort* dst = p1h + (size_t)j * KK;
    float ss = 0.f;
#pragma unroll
    for (int dy = 0; dy < 3; dy++) {
#pragma unroll
        for (int dx = 0; dx < 3; dx++) {
            int p = (jy + dy) * WW + (jx + dx);
            float v = gb[(size_t)p * DD + c] * mb[p];
            dst[(dy * 3 + dx) * DD + c] = f2bf(v);
            ss += v * v;
        }
    }
    ss = waveReduceSum(ss);
    if (c == 0) k1d[j] = ss;
}

// p1t[b, c(576), j(KPAD)] = p1h[b, j, c], zero-filled for j >= CC
__global__ __launch_bounds__(256) void transpose_p1(const ushort* __restrict__ p1h,
                                                    ushort* __restrict__ p1t) {
    __shared__ ushort T[64 * 65];
    int b = blockIdx.z;
    int j0 = blockIdx.x * 64;   // 34 tiles over CC
    int c0 = blockIdx.y * 64;   // 9 tiles over 576
    const ushort* src = p1h + (size_t)b * CC * KK;
    ushort* dst = p1t + (size_t)b * KK * KPAD;
    int t = threadIdx.x;
#pragma unroll
    for (int pass = 0; pass < 2; pass++) {
        int v = t + pass * 256;
        int r = v >> 3, c8 = (v & 7) * 8;
        int j = j0 + r;
        uint4 d = make_uint4(0, 0, 0, 0);
        if (j < CC) d = *(const uint4*)(src + (size_t)j * KK + c0 + c8);
        ushort tmp[8];
        *(uint4*)tmp = d;
#pragma unroll
        for (int u = 0; u < 8; u++) T[r * 65 + c8 + u] = tmp[u];
    }
    __syncthreads();
#pragma unroll
    for (int pass = 0; pass < 2; pass++) {
        int v = t + pass * 256;
        int cr = v >> 3, j8 = (v & 7) * 8;
        int outj = j0 + j8;
        if (outj + 8 <= KPAD) {
            ushort tmp[8];
#pragma unroll
            for (int u = 0; u < 8; u++) tmp[u] = T[(j8 + u) * 65 + cr];
            *(uint4*)(dst + (size_t)(c0 + cr) * KPAD + outj) = *(uint4*)tmp;
        }
    }
}

// ---------- GEMM1 (NT): S[m][n] = sum_k p2h[m][k] * p1h[n][k], fp16 out ----------
__global__ __launch_bounds__(256) void gemm1_nt(const ushort* __restrict__ A,
                                                const ushort* __restrict__ Bt,
                                                __half* __restrict__ Cout) {
    __shared__ ushort As[128 * 40];
    __shared__ ushort Bs[128 * 40];
    int b = blockIdx.z;
    const ushort* Ab = A + (size_t)b * HWp * KK;
    const ushort* Bb = Bt + (size_t)b * CC * KK;
    __half* C = Cout + (size_t)b * HWp * KPAD;
    int m0 = blockIdx.y * 128, n0 = blockIdx.x * 128;
    int tid = threadIdx.x;
    int lane = tid & 63, wid = tid >> 6;
    int quad = lane >> 4, l15 = lane & 15;
    int wm = (wid >> 1) * 64, wn = (wid & 1) * 64;

    float4v acc[4][4];
#pragma unroll
    for (int i = 0; i < 4; i++)
#pragma unroll
        for (int j = 0; j < 4; j++) acc[i][j] = (float4v){0.f, 0.f, 0.f, 0.f};

    int r0 = tid >> 2, c0 = (tid & 3) * 8;
    int r1 = (tid + 256) >> 2, c1 = (tid & 3) * 8;

    for (int k0 = 0; k0 < KK; k0 += 32) {
        uint4 da0 = *(const uint4*)(Ab + (size_t)(m0 + r0) * KK + k0 + c0);
        uint4 da1 = *(const uint4*)(Ab + (size_t)(m0 + r1) * KK + k0 + c1);
        uint4 db0 = make_uint4(0, 0, 0, 0), db1 = make_uint4(0, 0, 0, 0);
        if (n0 + r0 < CC) db0 = *(const uint4*)(Bb + (size_t)(n0 + r0) * KK + k0 + c0);
        if (n0 + r1 < CC) db1 = *(const uint4*)(Bb + (size_t)(n0 + r1) * KK + k0 + c1);
        *(uint4*)&As[r0 * 40 + c0] = da0;
        *(uint4*)&As[r1 * 40 + c1] = da1;
        *(uint4*)&Bs[r0 * 40 + c0] = db0;
        *(uint4*)&Bs[r1 * 40 + c1] = db1;
        __syncthreads();

        short8 af[4], bf[4];
#pragma unroll
        for (int i = 0; i < 4; i++)
            af[i] = *(const short8*)&As[(wm + i * 16 + l15) * 40 + quad * 8];
#pragma unroll
        for (int j = 0; j < 4; j++)
            bf[j] = *(const short8*)&Bs[(wn + j * 16 + l15) * 40 + quad * 8];
#pragma unroll
        for (int i = 0; i < 4; i++)
#pragma unroll
            for (int j = 0; j < 4; j++)
                acc[i][j] = __builtin_amdgcn_mfma_f32_16x16x32_bf16(af[i], bf[j], acc[i][j], 0, 0, 0);
        __syncthreads();
    }

#pragma unroll
    for (int i = 0; i < 4; i++) {
#pragma unroll
        for (int j = 0; j < 4; j++) {
            int n = n0 + wn + j * 16 + l15;
            if (n < CC) {
#pragma unroll
                for (int r = 0; r < 4; r++) {
                    int m = m0 + wm + i * 16 + quad * 4 + r;
                    C[(size_t)m * KPAD + n] = __float2half(acc[i][j][r]);
                }
            }
        }
    }
}

// ---------- GEMM2 split-K: aggS[m][n] = sum_{k in chunk} CA[m][k] * p1t[n][k] ----------
// grid.z = b*2 + split; 720 blocks total
__global__ __launch_bounds__(256) void gemm2_split(const ushort* __restrict__ A,
                                                   const ushort* __restrict__ Bt,
                                                   float* __restrict__ agg0,
                                                   float* __restrict__ agg1) {
    __shared__ ushort As[128 * 40];
    __shared__ ushort Bs[128 * 40];
    int z = blockIdx.z;
    int b = z >> 1, split = z & 1;
    const ushort* Ab = A + (size_t)b * HWp * KPAD;
    const ushort* Bb = Bt + (size_t)b * KK * KPAD;
    float* C = (split ? agg1 : agg0) + (size_t)b * HWp * KK;
    int kb = split ? KSPLIT0 : 0;
    int ke = split ? KPAD : KSPLIT0;
    int m0 = blockIdx.y * 128, n0 = blockIdx.x * 128;
    int tid = threadIdx.x;
    int lane = tid & 63, wid = tid >> 6;
    int quad = lane >> 4, l15 = lane & 15;
    int wm = (wid >> 1) * 64, wn = (wid & 1) * 64;

    float4v acc[4][4];
#pragma unroll
    for (int i = 0; i < 4; i++)
#pragma unroll
        for (int j = 0; j < 4; j++) acc[i][j] = (float4v){0.f, 0.f, 0.f, 0.f};

    int r0 = tid >> 2, c0 = (tid & 3) * 8;
    int r1 = (tid + 256) >> 2, c1 = (tid & 3) * 8;

    for (int k0 = kb; k0 < ke; k0 += 32) {
        uint4 da0 = *(const uint4*)(Ab + (size_t)(m0 + r0) * KPAD + k0 + c0);
        uint4 da1 = *(const uint4*)(Ab + (size_t)(m0 + r1) * KPAD + k0 + c1);
        uint4 db0 = make_uint4(0, 0, 0, 0), db1 = make_uint4(0, 0, 0, 0);
        if (n0 + r0 < KK) db0 = *(const uint4*)(Bb + (size_t)(n0 + r0) * KPAD + k0 + c0);
        if (n0 + r1 < KK) db1 = *(const uint4*)(Bb + (size_t)(n0 + r1) * KPAD + k0 + c1);
        *(uint4*)&As[r0 * 40 + c0] = da0;
        *(uint4*)&As[r1 * 40 + c1] = da1;
        *(uint4*)&Bs[r0 * 40 + c0] = db0;
        *(uint4*)&Bs[r1 * 40 + c1] = db1;
        __syncthreads();

        short8 af[4], bf[4];
#pragma unroll
        for (int i = 0; i < 4; i++)
            af[i] = *(const short8*)&As[(wm + i * 16 + l15) * 40 + quad * 8];
#pragma unroll
        for (int j = 0; j < 4; j++)
            bf[j] = *(const short8*)&Bs[(wn + j * 16 + l15) * 40 + quad * 8];
#pragma unroll
        for (int i = 0; i < 4; i++)
#pragma unroll
            for (int j = 0; j < 4; j++)
                acc[i][j] = __builtin_amdgcn_mfma_f32_16x16x32_bf16(af[i], bf[j], acc[i][j], 0, 0, 0);
        __syncthreads();
    }

#pragma unroll
    for (int i = 0; i < 4; i++) {
#pragma unroll
        for (int j = 0; j < 4; j++) {
            int n = n0 + wn + j * 16 + l15;
            if (n < KK) {
#pragma unroll
                for (int r = 0; r < 4; r++) {
                    int m = m0 + wm + i * 16 + quad * 4 + r;
                    C[(size_t)m * KK + n] = acc[i][j][r];
                }
            }
        }
    }
}

// ---------- row-wise: DS1 = k1d[n]-2*CS; standardize; -50*tanh; softmax (no max pass); bf16 CA ----------
__global__ __launch_bounds__(256) void rowsoft(void* __restrict__ Sbase,
                                               const float* __restrict__ k1d) {
    __shared__ float sm[4];
    size_t row = blockIdx.x;
    int b = (int)(row / HWp);
    const __half* p = (const __half*)Sbase + row * KPAD;
    ushort* wout = (ushort*)Sbase + row * KPAD;
    const float* k1 = k1d + (size_t)b * CC;
    int tid = threadIdx.x;
    float v[9];
#pragma unroll
    for (int i = 0; i < 9; i++) {
        int idx = tid + i * 256;
        v[i] = (idx < CC) ? (k1[idx] - 2.f * __half2float(p[idx])) : 0.f;
    }
    float s = 0.f;
#pragma unroll
    for (int i = 0; i < 9; i++) { int idx = tid + i * 256; if (idx < CC) s += v[i]; }
    s = blockReduceSum(s, sm);
    float mu = s / (float)CC;
    float vs = 0.f;
#pragma unroll
    for (int i = 0; i < 9; i++) {
        int idx = tid + i * 256;
        if (idx < CC) { float d = v[i] - mu; vs += d * d; }
    }
    vs = blockReduceSum(vs, sm);
    float inv_sd = 1.f / sqrtf(vs / (float)CC);
    // logits bounded in [-50,50]: exp without max-subtraction cannot overflow fp32
    float es = 0.f;
#pragma unroll
    for (int i = 0; i < 9; i++) {
        int idx = tid + i * 256;
        if (idx < CC) {
            v[i] = __expf(-50.f * fast_tanh((v[i] - mu) * inv_sd));
            es += v[i];
        }
    }
    es = blockReduceSum(es, sm);
    float invz = 1.f / es;
#pragma unroll
    for (int i = 0; i < 9; i++) {
        int idx = tid + i * 256;
        if (idx < KPAD) wout[idx] = (idx < CC) ? f2bf(v[i] * invz) : (ushort)0;
    }
}

// ---------- final: sum split partials, 9-shift combine, ACL, concat, W2 matmul, ELU ----------
__global__ __launch_bounds__(256) void final_k(const float* __restrict__ g,
                                               const float* __restrict__ mask,
                                               const float* __restrict__ agg0,
                                               const float* __restrict__ agg1,
                                               const float* __restrict__ W2,
                                               const float* __restrict__ b2,
                                               float* __restrict__ out) {
    int w = threadIdx.x >> 6, d = threadIdx.x & 63;
    int pix = blockIdx.x * 4 + w;
    int b = pix / HWp, yx = pix % HWp;
    int y = yx / WW, x = yx % WW;

    __shared__ float con1[4][128];
    float acl = 0.f;
#pragma unroll
    for (int dy = 0; dy < 3; dy++) {
#pragma unroll
        for (int dx = 0; dx < 3; dx++) {
            int yy = y + 1 - dy, xx = x + 1 - dx;
            if (yy >= 0 && yy < HH && xx >= 0 && xx < WW) {
                size_t off = ((size_t)(b * HWp + yy * WW + xx)) * KK + (dy * 3 + dx) * DD + d;
                acl += agg0[off] + agg1[off];
            }
        }
    }
    float m = mask[pix];
    float gv = g[(size_t)pix * DD + d];
    float bgv = gv * m;
    float ACL = bgv + (acl / 9.f) * (1.f - m);
    con1[w][d] = gv;
    con1[w][64 + d] = ACL;
    __syncthreads();
    float accv = b2[d];
#pragma unroll 8
    for (int k = 0; k < 128; k++) accv = fmaf(con1[w][k], W2[k * 64 + d], accv);
    out[(size_t)pix * DD + d] = accv > 0.f ? accv : expm1f(accv);
}

extern "C" void kernel_launch(void* const* d_in, const int* in_sizes, int n_in,
                              void* d_out, int out_size, void* d_ws, size_t ws_size,
                              hipStream_t stream) {
    const float* g    = (const float*)d_in[0];
    const float* mask = (const float*)d_in[1];
    const float* W2   = (const float*)d_in[2];
    const float* b2   = (const float*)d_in[3];
    float* out = (float*)d_out;
    char* ws = (char*)d_ws;

    ushort* p1h  = (ushort*)(ws + OFFB_P1H);
    ushort* p2h  = (ushort*)(ws + OFFB_P2H);
    ushort* p1t  = (ushort*)(ws + OFFB_P1T);
    float*  k1d  = (float*) (ws + OFFB_K1D);
    void*   S    = (void*)  (ws + OFFB_S);     // fp16 CS, then bf16 CA in place
    float*  agg0 = (float*) (ws + OFFB_AGG0);
    float*  agg1 = (float*) (ws + OFFB_AGG1);

    build_p2<<<BB * HWp / 4, 256, 0, stream>>>(g, p2h);
    build_p1<<<BB * CC / 4, 256, 0, stream>>>(g, mask, p1h, k1d);
    transpose_p1<<<dim3(34, 9, BB), 256, 0, stream>>>(p1h, p1t);

    gemm1_nt<<<dim3(17, 18, BB), 256, 0, stream>>>(p2h, p1h, (__half*)S);

    rowsoft<<<BB * HWp, 256, 0, stream>>>(S, k1d);

    gemm2_split<<<dim3(5, 18, BB * 2), 256, 0, stream>>>((const ushort*)S, p1t, agg0, agg1);

    final_k<<<BB * HWp / 4, 256, 0, stream>>>(g, mask, agg0, agg1, W2, b2, out);
}

// Round 4
// 215.554 us; speedup vs baseline: 5.1570x; 1.0153x over previous
//
#include <hip/hip_runtime.h>
#include <hip/hip_fp16.h>
#include <math.h>

// Problem constants
#define BB 4
#define HH 48
#define WW 48
#define DD 64
#define CH 46
#define CWp 46
#define CC (CH*CWp)      // 2116
#define KK 576           // 9*64
#define HWp (HH*WW)      // 2304
#define KPAD 2144        // 67*32, padded K for GEMM2 / row stride of S & CA
#define KSPLIT0 1088     // 34*32; chunk1 = [1088,2144) = 33 iters

typedef __attribute__((ext_vector_type(8))) short short8;
typedef __attribute__((ext_vector_type(4))) float float4v;

// ---------- workspace layout (byte offsets, all 16B-aligned) ----------
#define OFFB_P1H  ((size_t)0)              // bf16 [B][CC][576]      9,750,528 B
#define OFFB_P2H  ((size_t)9750528)        // bf16 [B][HW][576]     10,616,832 B
#define OFFB_P1T  ((size_t)20367360)       // bf16 [B][576][KPAD]    9,879,552 B
#define OFFB_K1D  ((size_t)30246912)       // fp32 [B][CC]              33,856 B
#define OFFB_S    ((size_t)30280768)       // fp16 CS -> bf16 CA [B][HW][KPAD] 39,518,208 B
#define OFFB_AGG0 ((size_t)69798976)       // fp32 [B][HW][576]     21,233,664 B
#define OFFB_AGG1 ((size_t)91032640)       // fp32 [B][HW][576]     21,233,664 B
// total 112,266,304 B

// ---------- helpers ----------
__device__ __forceinline__ ushort f2bf(float x) {
    unsigned u = __float_as_uint(x);
    return (ushort)((u + 0x7FFFu + ((u >> 16) & 1u)) >> 16);
}

__device__ __forceinline__ float waveReduceSum(float x) {
#pragma unroll
    for (int o = 32; o > 0; o >>= 1) x += __shfl_down(x, o, 64);
    return x;
}

__device__ __forceinline__ float blockReduceSum(float x, float* sm) {
#pragma unroll
    for (int o = 32; o > 0; o >>= 1) x += __shfl_down(x, o, 64);
    int lane = threadIdx.x & 63, w = threadIdx.x >> 6;
    __syncthreads();
    if (lane == 0) sm[w] = x;
    __syncthreads();
    return sm[0] + sm[1] + sm[2] + sm[3];
}

// fast tanh via hardware exp: tanh(z) = 1 - 2/(e^{2z}+1)
__device__ __forceinline__ float fast_tanh(float z) {
    float e = __expf(2.f * z);
    return 1.f - 2.f / (e + 1.f);
}

// async 16B global->LDS (wave-uniform LDS base + lane*16)
typedef __attribute__((address_space(3))) void lds_void_t;
typedef __attribute__((address_space(1))) void gmem_void_t;
__device__ __forceinline__ void gld16(const ushort* g, ushort* lds) {
    __builtin_amdgcn_global_load_lds((gmem_void_t*)g, (lds_void_t*)lds, 16, 0, 0);
}

// ---------- prep kernels (256 thr = 4 pixels/block, one wave each) ----------
__global__ __launch_bounds__(256) void build_p2(const float* __restrict__ g,
                                                ushort* __restrict__ p2h) {
    int pix = blockIdx.x * 4 + (threadIdx.x >> 6);
    int b = pix / HWp, yx = pix % HWp;
    int y = yx / WW, x = yx % WW;
    int c = threadIdx.x & 63;
    const float* gb = g + (size_t)b * HWp * DD;
    ushort* dst = p2h + (size_t)pix * KK;
#pragma unroll
    for (int dy = 0; dy < 3; dy++) {
#pragma unroll
        for (int dx = 0; dx < 3; dx++) {
            int yy = y + dy - 1, xx = x + dx - 1;
            float v = (yy >= 0 && yy < HH && xx >= 0 && xx < WW)
                          ? gb[((size_t)yy * WW + xx) * DD + c] : 0.f;
            dst[(dy * 3 + dx) * DD + c] = f2bf(v);
        }
    }
}

__global__ __launch_bounds__(256) void build_p1(const float* __restrict__ g,
                                                const float* __restrict__ mask,
                                                ushort* __restrict__ p1h,
                                                float* __restrict__ k1d) {
    int j = blockIdx.x * 4 + (threadIdx.x >> 6);
    int b = j / CC, jj = j % CC;
    int jy = jj / CWp, jx = jj % CWp;
    int c = threadIdx.x & 63;
    const float* gb = g + (size_t)b * HWp * DD;
    const float* mb = mask + (size_t)b * HWp;
    ushort* dst = p1h + (size_t)j * KK;
    float ss = 0.f;
#pragma unroll
    for (int dy = 0; dy < 3; dy++) {
#pragma unroll
        for (int dx = 0; dx < 3; dx++) {
            int p = (jy + dy) * WW + (jx + dx);
            float v = gb[(size_t)p * DD + c] * mb[p];
            dst[(dy * 3 + dx) * DD + c] = f2bf(v);
            ss += v * v;
        }
    }
    ss = waveReduceSum(ss);
    if (c == 0) k1d[j] = ss;
}

// p1t[b, c(576), j(KPAD)] = p1h[b, j, c], zero-filled for j >= CC
__global__ __launch_bounds__(256) void transpose_p1(const ushort* __restrict__ p1h,
                                                    ushort* __restrict__ p1t) {
    __shared__ ushort T[64 * 65];
    int b = blockIdx.z;
    int j0 = blockIdx.x * 64;
    int c0 = blockIdx.y * 64;
    const ushort* src = p1h + (size_t)b * CC * KK;
    ushort* dst = p1t + (size_t)b * KK * KPAD;
    int t = threadIdx.x;
#pragma unroll
    for (int pass = 0; pass < 2; pass++) {
        int v = t + pass * 256;
        int r = v >> 3, c8 = (v & 7) * 8;
        int j = j0 + r;
        uint4 d = make_uint4(0, 0, 0, 0);
        if (j < CC) d = *(const uint4*)(src + (size_t)j * KK + c0 + c8);
        ushort tmp[8];
        *(uint4*)tmp = d;
#pragma unroll
        for (int u = 0; u < 8; u++) T[r * 65 + c8 + u] = tmp[u];
    }
    __syncthreads();
#pragma unroll
    for (int pass = 0; pass < 2; pass++) {
        int v = t + pass * 256;
        int cr = v >> 3, j8 = (v & 7) * 8;
        int outj = j0 + j8;
        if (outj + 8 <= KPAD) {
            ushort tmp[8];
#pragma unroll
            for (int u = 0; u < 8; u++) tmp[u] = T[(j8 + u) * 65 + cr];
            *(uint4*)(dst + (size_t)(c0 + cr) * KPAD + outj) = *(uint4*)tmp;
        }
    }
}

// ---------- shared MFMA GEMM core (NT), async-staged, XOR-swizzled LDS ----------
// LDS tiles: [128 rows][32 k] ushort, unpadded. LDS[r][pos16B] holds global
// chunk pos^((r>>1)&3); fragment read uses chunk quad^((l15>>1)&3).
__device__ __forceinline__ void gemm_tile(const ushort* __restrict__ Ab,   // += m0*lda already
                                          const ushort* __restrict__ Bb,   // += n0*ldb already
                                          int lda, int ldb, int kb, int ke,
                                          int Nrem,                        // valid B rows in this tile
                                          ushort* As, ushort* Bs,
                                          float4v (&acc)[4][4]) {
    int tid = threadIdx.x;
    int l64 = tid & 63, w = tid >> 6;
    int quad = l64 >> 4, l15 = l64 & 15;
    int wm = (w >> 1) * 64, wn = (w & 1) * 64;
    int rowInC = l64 >> 2;                       // 0..15
    int cSw = (l64 & 3) ^ ((l64 >> 3) & 3);      // swizzled source 16B chunk
    int chunk0 = w * 2, chunk1 = w * 2 + 1;
    int r0 = chunk0 * 16 + rowInC, r1 = chunk1 * 16 + rowInC;
    int sw8 = (l15 >> 1) & 3;

    const ushort* a0 = Ab + (size_t)r0 * lda + cSw * 8;
    const ushort* a1 = Ab + (size_t)r1 * lda + cSw * 8;
    const ushort* b0 = Bb + (size_t)r0 * ldb + cSw * 8;
    const ushort* b1 = Bb + (size_t)r1 * ldb + cSw * 8;
    bool gb0 = r0 < Nrem, gb1 = r1 < Nrem;
    ushort* lA0 = As + chunk0 * 512;   // 1024 B per wave-chunk
    ushort* lA1 = As + chunk1 * 512;
    ushort* lB0 = Bs + chunk0 * 512;
    ushort* lB1 = Bs + chunk1 * 512;

    for (int k0 = kb; k0 < ke; k0 += 32) {
        gld16(a0 + k0, lA0);
        gld16(a1 + k0, lA1);
        if (gb0) gld16(b0 + k0, lB0);
        if (gb1) gld16(b1 + k0, lB1);
        __syncthreads();          // compiler emits vmcnt drain before barrier

        short8 af[4], bf[4];
#pragma unroll
        for (int i = 0; i < 4; i++)
            af[i] = *(const short8*)&As[(wm + i * 16 + l15) * 32 + (quad ^ sw8) * 8];
#pragma unroll
        for (int j = 0; j < 4; j++)
            bf[j] = *(const short8*)&Bs[(wn + j * 16 + l15) * 32 + (quad ^ sw8) * 8];
#pragma unroll
        for (int i = 0; i < 4; i++)
#pragma unroll
            for (int j = 0; j < 4; j++)
                acc[i][j] = __builtin_amdgcn_mfma_f32_16x16x32_bf16(af[i], bf[j], acc[i][j], 0, 0, 0);
        __syncthreads();
    }
}

// ---------- GEMM1: S[m][n] = sum_k p2h[m][k]*p1h[n][k], fp16 out ----------
__global__ __launch_bounds__(256) void gemm1_nt(const ushort* __restrict__ A,
                                                const ushort* __restrict__ Bt,
                                                __half* __restrict__ Cout) {
    __shared__ ushort As[128 * 32];
    __shared__ ushort Bs[128 * 32];
    int b = blockIdx.z;
    int m0 = blockIdx.y * 128, n0 = blockIdx.x * 128;
    const ushort* Ab = A + (size_t)b * HWp * KK + (size_t)m0 * KK;
    const ushort* Bb = Bt + (size_t)b * CC * KK + (size_t)n0 * KK;
    float4v acc[4][4];
#pragma unroll
    for (int i = 0; i < 4; i++)
#pragma unroll
        for (int j = 0; j < 4; j++) acc[i][j] = (float4v){0.f, 0.f, 0.f, 0.f};

    gemm_tile(Ab, Bb, KK, KK, 0, KK, CC - n0, As, Bs, acc);

    int tid = threadIdx.x;
    int lane = tid & 63, wid = tid >> 6;
    int quad = lane >> 4, l15 = lane & 15;
    int wm = (wid >> 1) * 64, wn = (wid & 1) * 64;
    __half* C = Cout + (size_t)b * HWp * KPAD;
#pragma unroll
    for (int i = 0; i < 4; i++) {
#pragma unroll
        for (int j = 0; j < 4; j++) {
            int n = n0 + wn + j * 16 + l15;
            if (n < CC) {
#pragma unroll
                for (int r = 0; r < 4; r++) {
                    int m = m0 + wm + i * 16 + quad * 4 + r;
                    C[(size_t)m * KPAD + n] = __float2half(acc[i][j][r]);
                }
            }
        }
    }
}

// ---------- GEMM2 split-K: agg{0,1}[m][n] = sum_{k chunk} CA[m][k]*p1t[n][k] ----------
__global__ __launch_bounds__(256) void gemm2_split(const ushort* __restrict__ A,
                                                   const ushort* __restrict__ Bt,
                                                   float* __restrict__ agg0,
                                                   float* __restrict__ agg1) {
    __shared__ ushort As[128 * 32];
    __shared__ ushort Bs[128 * 32];
    int z = blockIdx.z;
    int b = z >> 1, split = z & 1;
    int m0 = blockIdx.y * 128, n0 = blockIdx.x * 128;
    const ushort* Ab = A + (size_t)b * HWp * KPAD + (size_t)m0 * KPAD;
    const ushort* Bb = Bt + (size_t)b * KK * KPAD + (size_t)n0 * KPAD;
    float4v acc[4][4];
#pragma unroll
    for (int i = 0; i < 4; i++)
#pragma unroll
        for (int j = 0; j < 4; j++) acc[i][j] = (float4v){0.f, 0.f, 0.f, 0.f};

    gemm_tile(Ab, Bb, KPAD, KPAD, split ? KSPLIT0 : 0, split ? KPAD : KSPLIT0,
              KK - n0, As, Bs, acc);

    int tid = threadIdx.x;
    int lane = tid & 63, wid = tid >> 6;
    int quad = lane >> 4, l15 = lane & 15;
    int wm = (wid >> 1) * 64, wn = (wid & 1) * 64;
    float* C = (split ? agg1 : agg0) + (size_t)b * HWp * KK;
#pragma unroll
    for (int i = 0; i < 4; i++) {
#pragma unroll
        for (int j = 0; j < 4; j++) {
            int n = n0 + wn + j * 16 + l15;
            if (n < KK) {
#pragma unroll
                for (int r = 0; r < 4; r++) {
                    int m = m0 + wm + i * 16 + quad * 4 + r;
                    C[(size_t)m * KK + n] = acc[i][j][r];
                }
            }
        }
    }
}

// ---------- row-wise: DS1 = k1d[n]-2*CS; standardize; -50*tanh; softmax; bf16 CA ----------
__global__ __launch_bounds__(256) void rowsoft(void* __restrict__ Sbase,
                                               const float* __restrict__ k1d) {
    __shared__ float sm[4];
    size_t row = blockIdx.x;
    int b = (int)(row / HWp);
    const __half* p = (const __half*)Sbase + row * KPAD;
    ushort* wout = (ushort*)Sbase + row * KPAD;
    const float* k1 = k1d + (size_t)b * CC;
    int tid = threadIdx.x;
    float v[9];
#pragma unroll
    for (int i = 0; i < 9; i++) {
        int idx = tid + i * 256;
        v[i] = (idx < CC) ? (k1[idx] - 2.f * __half2float(p[idx])) : 0.f;
    }
    float s = 0.f;
#pragma unroll
    for (int i = 0; i < 9; i++) { int idx = tid + i * 256; if (idx < CC) s += v[i]; }
    s = blockReduceSum(s, sm);
    float mu = s / (float)CC;
    float vs = 0.f;
#pragma unroll
    for (int i = 0; i < 9; i++) {
        int idx = tid + i * 256;
        if (idx < CC) { float d = v[i] - mu; vs += d * d; }
    }
    vs = blockReduceSum(vs, sm);
    float inv_sd = 1.f / sqrtf(vs / (float)CC);
    // logits bounded in [-50,50]: exp without max-subtraction cannot overflow fp32
    float es = 0.f;
#pragma unroll
    for (int i = 0; i < 9; i++) {
        int idx = tid + i * 256;
        if (idx < CC) {
            v[i] = __expf(-50.f * fast_tanh((v[i] - mu) * inv_sd));
            es += v[i];
        }
    }
    es = blockReduceSum(es, sm);
    float invz = 1.f / es;
#pragma unroll
    for (int i = 0; i < 9; i++) {
        int idx = tid + i * 256;
        if (idx < KPAD) wout[idx] = (idx < CC) ? f2bf(v[i] * invz) : (ushort)0;
    }
}

// ---------- final: sum split partials, 9-shift combine, ACL, concat, W2, ELU ----------
__global__ __launch_bounds__(256) void final_k(const float* __restrict__ g,
                                               const float* __restrict__ mask,
                                               const float* __restrict__ agg0,
                                               const float* __restrict__ agg1,
                                               const float* __restrict__ W2,
                                               const float* __restrict__ b2,
                                               float* __restrict__ out) {
    int w = threadIdx.x >> 6, d = threadIdx.x & 63;
    int pix = blockIdx.x * 4 + w;
    int b = pix / HWp, yx = pix % HWp;
    int y = yx / WW, x = yx % WW;

    __shared__ float con1[4][128];
    float acl = 0.f;
#pragma unroll
    for (int dy = 0; dy < 3; dy++) {
#pragma unroll
        for (int dx = 0; dx < 3; dx++) {
            int yy = y + 1 - dy, xx = x + 1 - dx;
            if (yy >= 0 && yy < HH && xx >= 0 && xx < WW) {
                size_t off = ((size_t)(b * HWp + yy * WW + xx)) * KK + (dy * 3 + dx) * DD + d;
                acl += agg0[off] + agg1[off];
            }
        }
    }
    float m = mask[pix];
    float gv = g[(size_t)pix * DD + d];
    float bgv = gv * m;
    float ACL = bgv + (acl / 9.f) * (1.f - m);
    con1[w][d] = gv;
    con1[w][64 + d] = ACL;
    __syncthreads();
    float accv = b2[d];
#pragma unroll 8
    for (int k = 0; k < 128; k++) accv = fmaf(con1[w][k], W2[k * 64 + d], accv);
    out[(size_t)pix * DD + d] = accv > 0.f ? accv : expm1f(accv);
}

extern "C" void kernel_launch(void* const* d_in, const int* in_sizes, int n_in,
                              void* d_out, int out_size, void* d_ws, size_t ws_size,
                              hipStream_t stream) {
    const float* g    = (const float*)d_in[0];
    const float* mask = (const float*)d_in[1];
    const float* W2   = (const float*)d_in[2];
    const float* b2   = (const float*)d_in[3];
    float* out = (float*)d_out;
    char* ws = (char*)d_ws;

    ushort* p1h  = (ushort*)(ws + OFFB_P1H);
    ushort* p2h  = (ushort*)(ws + OFFB_P2H);
    ushort* p1t  = (ushort*)(ws + OFFB_P1T);
    float*  k1d  = (float*) (ws + OFFB_K1D);
    void*   S    = (void*)  (ws + OFFB_S);     // fp16 CS, then bf16 CA in place
    float*  agg0 = (float*) (ws + OFFB_AGG0);
    float*  agg1 = (float*) (ws + OFFB_AGG1);

    build_p2<<<BB * HWp / 4, 256, 0, stream>>>(g, p2h);
    build_p1<<<BB * CC / 4, 256, 0, stream>>>(g, mask, p1h, k1d);
    transpose_p1<<<dim3(34, 9, BB), 256, 0, stream>>>(p1h, p1t);

    gemm1_nt<<<dim3(17, 18, BB), 256, 0, stream>>>(p2h, p1h, (__half*)S);

    rowsoft<<<BB * HWp, 256, 0, stream>>>(S, k1d);

    gemm2_split<<<dim3(5, 18, BB * 2), 256, 0, stream>>>((const ushort*)S, p1t, agg0, agg1);

    final_k<<<BB * HWp / 4, 256, 0, stream>>>(g, mask, agg0, agg1, W2, b2, out);
}

// Round 5
// 208.729 us; speedup vs baseline: 5.3256x; 1.0327x over previous
//
#include <hip/hip_runtime.h>
#include <hip/hip_fp16.h>
#include <math.h>

// Problem constants
#define BB 4
#define HH 48
#define WW 48
#define DD 64
#define CH 46
#define CWp 46
#define CC (CH*CWp)      // 2116
#define KK 576           // 9*64
#define HWp (HH*WW)      // 2304
#define KPAD 2176        // 34*64: row stride of S & CA, padded K for GEMM2
#define KSPLIT0 1088     // 17*64; chunk1 = [1088,2176) = 17 iters

typedef __attribute__((ext_vector_type(8))) short short8;
typedef __attribute__((ext_vector_type(4))) float float4v;

// ---------- workspace layout (byte offsets, all 16B-aligned) ----------
#define OFFB_P1H  ((size_t)0)              // bf16 [B][CC][576]       9,750,528 B
#define OFFB_P2H  ((size_t)9750528)        // bf16 [B][HW][576]      10,616,832 B
#define OFFB_P1T  ((size_t)20367360)       // bf16 [B][576][KPAD]    10,027,008 B
#define OFFB_K1D  ((size_t)30394368)       // fp32 [B][CC]               33,856 B
#define OFFB_S    ((size_t)30428224)       // fp16 CS -> bf16 CA [B][HW][KPAD] 40,108,032 B
#define OFFB_AGG0 ((size_t)70536256)       // fp16 [B][HW][576]      10,616,832 B
#define OFFB_AGG1 ((size_t)81153088)       // fp16 [B][HW][576]      10,616,832 B
// total 91,769,920 B

// ---------- helpers ----------
__device__ __forceinline__ ushort f2bf(float x) {
    unsigned u = __float_as_uint(x);
    return (ushort)((u + 0x7FFFu + ((u >> 16) & 1u)) >> 16);
}

__device__ __forceinline__ float waveReduceSum(float x) {
#pragma unroll
    for (int o = 32; o > 0; o >>= 1) x += __shfl_down(x, o, 64);
    return x;
}

__device__ __forceinline__ float blockReduceSum(float x, float* sm) {
#pragma unroll
    for (int o = 32; o > 0; o >>= 1) x += __shfl_down(x, o, 64);
    int lane = threadIdx.x & 63, w = threadIdx.x >> 6;
    __syncthreads();
    if (lane == 0) sm[w] = x;
    __syncthreads();
    return sm[0] + sm[1] + sm[2] + sm[3];
}

// fast tanh via hardware exp: tanh(z) = 1 - 2/(e^{2z}+1)
__device__ __forceinline__ float fast_tanh(float z) {
    float e = __expf(2.f * z);
    return 1.f - 2.f / (e + 1.f);
}

// async 16B global->LDS (wave-uniform LDS base + lane*16)
typedef __attribute__((address_space(3))) void lds_void_t;
typedef __attribute__((address_space(1))) void gmem_void_t;
__device__ __forceinline__ void gld16(const ushort* g, ushort* lds) {
    __builtin_amdgcn_global_load_lds((gmem_void_t*)g, (lds_void_t*)lds, 16, 0, 0);
}

// ---------- prep kernels (256 thr = 4 pixels/block, one wave each) ----------
__global__ __launch_bounds__(256) void build_p2(const float* __restrict__ g,
                                                ushort* __restrict__ p2h) {
    int pix = blockIdx.x * 4 + (threadIdx.x >> 6);
    int b = pix / HWp, yx = pix % HWp;
    int y = yx / WW, x = yx % WW;
    int c = threadIdx.x & 63;
    const float* gb = g + (size_t)b * HWp * DD;
    ushort* dst = p2h + (size_t)pix * KK;
#pragma unroll
    for (int dy = 0; dy < 3; dy++) {
#pragma unroll
        for (int dx = 0; dx < 3; dx++) {
            int yy = y + dy - 1, xx = x + dx - 1;
            float v = (yy >= 0 && yy < HH && xx >= 0 && xx < WW)
                          ? gb[((size_t)yy * WW + xx) * DD + c] : 0.f;
            dst[(dy * 3 + dx) * DD + c] = f2bf(v);
        }
    }
}

__global__ __launch_bounds__(256) void build_p1(const float* __restrict__ g,
                                                const float* __restrict__ mask,
                                                ushort* __restrict__ p1h,
                                                float* __restrict__ k1d) {
    int j = blockIdx.x * 4 + (threadIdx.x >> 6);
    int b = j / CC, jj = j % CC;
    int jy = jj / CWp, jx = jj % CWp;
    int c = threadIdx.x & 63;
    const float* gb = g + (size_t)b * HWp * DD;
    const float* mb = mask + (size_t)b * HWp;
    ushort* dst = p1h + (size_t)j * KK;
    float ss = 0.f;
#pragma unroll
    for (int dy = 0; dy < 3; dy++) {
#pragma unroll
        for (int dx = 0; dx < 3; dx++) {
            int p = (jy + dy) * WW + (jx + dx);
            float v = gb[(size_t)p * DD + c] * mb[p];
            dst[(dy * 3 + dx) * DD + c] = f2bf(v);
            ss += v * v;
        }
    }
    ss = waveReduceSum(ss);
    if (c == 0) k1d[j] = ss;
}

// p1t[b, c(576), j(KPAD)] = p1h[b, j, c], zero-filled for j >= CC
__global__ __launch_bounds__(256) void transpose_p1(const ushort* __restrict__ p1h,
                                                    ushort* __restrict__ p1t) {
    __shared__ ushort T[64 * 65];
    int b = blockIdx.z;
    int j0 = blockIdx.x * 64;   // 34 tiles * 64 = 2176 = KPAD
    int c0 = blockIdx.y * 64;
    const ushort* src = p1h + (size_t)b * CC * KK;
    ushort* dst = p1t + (size_t)b * KK * KPAD;
    int t = threadIdx.x;
#pragma unroll
    for (int pass = 0; pass < 2; pass++) {
        int v = t + pass * 256;
        int r = v >> 3, c8 = (v & 7) * 8;
        int j = j0 + r;
        uint4 d = make_uint4(0, 0, 0, 0);
        if (j < CC) d = *(const uint4*)(src + (size_t)j * KK + c0 + c8);
        ushort tmp[8];
        *(uint4*)tmp = d;
#pragma unroll
        for (int u = 0; u < 8; u++) T[r * 65 + c8 + u] = tmp[u];
    }
    __syncthreads();
#pragma unroll
    for (int pass = 0; pass < 2; pass++) {
        int v = t + pass * 256;
        int cr = v >> 3, j8 = (v & 7) * 8;
        ushort tmp[8];
#pragma unroll
        for (int u = 0; u < 8; u++) tmp[u] = T[(j8 + u) * 65 + cr];
        *(uint4*)(dst + (size_t)(c0 + cr) * KPAD + j0 + j8) = *(uint4*)tmp;
    }
}

// ---------- shared MFMA GEMM core (NT layout), BK=64, async-staged, XOR-swizzled ----------
// LDS rows of 64 ushort (8 x 16B chunks). LDS[r][p] = global chunk (p&4)|((p&3)^((r>>1)&3)).
// One gld16 inst stages 8 full rows (64 lanes x 16B = 1 KB contiguous).
// NBI = B-tile staging insts per wave = Btile_rows/32 (4 -> 128 rows, 6 -> 192 rows).
template <int NBI, bool NMASK>
__device__ __forceinline__ void gemm_tile64(const ushort* __restrict__ Ab,   // += m0*lda
                                            const ushort* __restrict__ Bb,   // += n0*ldb
                                            int lda, int ldb, int kb, int ke,
                                            int Nrem,
                                            ushort* As, ushort* Bs,
                                            float4v (&acc)[4][NBI]) {
    int tid = threadIdx.x;
    int l = tid & 63, w = tid >> 6;
    int quad = l >> 4, l15 = l & 15;
    int sw8 = (l15 >> 1) & 3;
    int wm = (w >> 1) * 64, wn = (w & 1) * (NBI * 16);
    // staging source mapping: row-in-group = l>>3, global chunk with XOR swizzle
    int sr = l >> 3;
    int gch = (l & 4) | ((l & 3) ^ ((l >> 4) & 3));

    for (int k0 = kb; k0 < ke; k0 += 64) {
#pragma unroll
        for (int i = 0; i < 4; i++) {
            int rg = 4 * w + i;
            int r = rg * 8 + sr;
            gld16(Ab + (size_t)r * lda + k0 + gch * 8, As + rg * 512);
        }
#pragma unroll
        for (int i = 0; i < NBI; i++) {
            int rg = NBI * w + i;
            int r = rg * 8 + sr;
            if (!NMASK || r < Nrem)
                gld16(Bb + (size_t)r * ldb + k0 + gch * 8, Bs + rg * 512);
        }
        __syncthreads();   // compiler drains vmcnt before barrier

#pragma unroll
        for (int h = 0; h < 2; h++) {
            short8 af[4], bf[NBI];
#pragma unroll
            for (int i = 0; i < 4; i++)
                af[i] = *(const short8*)&As[(wm + i * 16 + l15) * 64 + h * 32 + ((quad ^ sw8)) * 8];
#pragma unroll
            for (int j = 0; j < NBI; j++)
                bf[j] = *(const short8*)&Bs[(wn + j * 16 + l15) * 64 + h * 32 + ((quad ^ sw8)) * 8];
#pragma unroll
            for (int i = 0; i < 4; i++)
#pragma unroll
                for (int j = 0; j < NBI; j++)
                    acc[i][j] = __builtin_amdgcn_mfma_f32_16x16x32_bf16(af[i], bf[j], acc[i][j], 0, 0, 0);
        }
        __syncthreads();
    }
}

// ---------- GEMM1: S[m][n] = sum_k p2h[m][k]*p1h[n][k], fp16 out, 128x128 tiles ----------
__global__ __launch_bounds__(256) void gemm1_nt(const ushort* __restrict__ A,
                                                const ushort* __restrict__ Bt,
                                                __half* __restrict__ Cout) {
    __shared__ ushort As[128 * 64];
    __shared__ ushort Bs[128 * 64];
    int b = blockIdx.z;
    int m0 = blockIdx.y * 128, n0 = blockIdx.x * 128;
    const ushort* Ab = A + (size_t)b * HWp * KK + (size_t)m0 * KK;
    const ushort* Bb = Bt + (size_t)b * CC * KK + (size_t)n0 * KK;
    float4v acc[4][4];
#pragma unroll
    for (int i = 0; i < 4; i++)
#pragma unroll
        for (int j = 0; j < 4; j++) acc[i][j] = (float4v){0.f, 0.f, 0.f, 0.f};

    gemm_tile64<4, true>(Ab, Bb, KK, KK, 0, KK, CC - n0, As, Bs, acc);

    int tid = threadIdx.x;
    int lane = tid & 63, wid = tid >> 6;
    int quad = lane >> 4, l15 = lane & 15;
    int wm = (wid >> 1) * 64, wn = (wid & 1) * 64;
    __half* C = Cout + (size_t)b * HWp * KPAD;
#pragma unroll
    for (int i = 0; i < 4; i++) {
#pragma unroll
        for (int j = 0; j < 4; j++) {
            int n = n0 + wn + j * 16 + l15;
            if (n < CC) {
#pragma unroll
                for (int r = 0; r < 4; r++) {
                    int m = m0 + wm + i * 16 + quad * 4 + r;
                    C[(size_t)m * KPAD + n] = __float2half(acc[i][j][r]);
                }
            }
        }
    }
}

// ---------- GEMM2 split-K: agg{0,1}[m][n] = sum_{k chunk} CA[m][k]*p1t[n][k] ----------
// 128m x 192n tiles (576 = 3*192, no n-masking needed), fp16 partial outputs
__global__ __launch_bounds__(256) void gemm2_split(const ushort* __restrict__ A,
                                                   const ushort* __restrict__ Bt,
                                                   __half* __restrict__ agg0,
                                                   __half* __restrict__ agg1) {
    __shared__ ushort As[128 * 64];
    __shared__ ushort Bs[192 * 64];
    int z = blockIdx.z;
    int b = z >> 1, split = z & 1;
    int m0 = blockIdx.y * 128, n0 = blockIdx.x * 192;
    const ushort* Ab = A + (size_t)b * HWp * KPAD + (size_t)m0 * KPAD;
    const ushort* Bb = Bt + (size_t)b * KK * KPAD + (size_t)n0 * KPAD;
    float4v acc[4][6];
#pragma unroll
    for (int i = 0; i < 4; i++)
#pragma unroll
        for (int j = 0; j < 6; j++) acc[i][j] = (float4v){0.f, 0.f, 0.f, 0.f};

    gemm_tile64<6, false>(Ab, Bb, KPAD, KPAD, split ? KSPLIT0 : 0,
                          split ? KPAD : KSPLIT0, 192, As, Bs, acc);

    int tid = threadIdx.x;
    int lane = tid & 63, wid = tid >> 6;
    int quad = lane >> 4, l15 = lane & 15;
    int wm = (wid >> 1) * 64, wn = (wid & 1) * 96;
    __half* C = (split ? agg1 : agg0) + (size_t)b * HWp * KK;
#pragma unroll
    for (int i = 0; i < 4; i++) {
#pragma unroll
        for (int j = 0; j < 6; j++) {
            int n = n0 + wn + j * 16 + l15;
#pragma unroll
            for (int r = 0; r < 4; r++) {
                int m = m0 + wm + i * 16 + quad * 4 + r;
                C[(size_t)m * KK + n] = __float2half(acc[i][j][r]);
            }
        }
    }
}

// ---------- row-wise: DS1 = k1d[n]-2*CS; standardize; -50*tanh; softmax; bf16 CA ----------
__global__ __launch_bounds__(256) void rowsoft(void* __restrict__ Sbase,
                                               const float* __restrict__ k1d) {
    __shared__ float sm[4];
    size_t row = blockIdx.x;
    int b = (int)(row / HWp);
    const __half* p = (const __half*)Sbase + row * KPAD;
    ushort* wout = (ushort*)Sbase + row * KPAD;
    const float* k1 = k1d + (size_t)b * CC;
    int tid = threadIdx.x;
    float v[9];
#pragma unroll
    for (int i = 0; i < 9; i++) {
        int idx = tid + i * 256;
        v[i] = (idx < CC) ? (k1[idx] - 2.f * __half2float(p[idx])) : 0.f;
    }
    float s = 0.f;
#pragma unroll
    for (int i = 0; i < 9; i++) { int idx = tid + i * 256; if (idx < CC) s += v[i]; }
    s = blockReduceSum(s, sm);
    float mu = s / (float)CC;
    float vs = 0.f;
#pragma unroll
    for (int i = 0; i < 9; i++) {
        int idx = tid + i * 256;
        if (idx < CC) { float d = v[i] - mu; vs += d * d; }
    }
    vs = blockReduceSum(vs, sm);
    float inv_sd = 1.f / sqrtf(vs / (float)CC);
    // logits bounded in [-50,50]: exp without max-subtraction cannot overflow fp32
    float es = 0.f;
#pragma unroll
    for (int i = 0; i < 9; i++) {
        int idx = tid + i * 256;
        if (idx < CC) {
            v[i] = __expf(-50.f * fast_tanh((v[i] - mu) * inv_sd));
            es += v[i];
        }
    }
    es = blockReduceSum(es, sm);
    float invz = 1.f / es;
#pragma unroll
    for (int i = 0; i < 9; i++) {
        int idx = tid + i * 256;
        if (idx < KPAD) wout[idx] = (idx < CC) ? f2bf(v[i] * invz) : (ushort)0;
    }
}

// ---------- final: sum split partials, 9-shift combine, ACL, concat, W2, ELU ----------
__global__ __launch_bounds__(256) void final_k(const float* __restrict__ g,
                                               const float* __restrict__ mask,
                                               const __half* __restrict__ agg0,
                                               const __half* __restrict__ agg1,
                                               const float* __restrict__ W2,
                                               const float* __restrict__ b2,
                                               float* __restrict__ out) {
    int w = threadIdx.x >> 6, d = threadIdx.x & 63;
    int pix = blockIdx.x * 4 + w;
    int b = pix / HWp, yx = pix % HWp;
    int y = yx / WW, x = yx % WW;

    __shared__ float con1[4][128];
    float acl = 0.f;
#pragma unroll
    for (int dy = 0; dy < 3; dy++) {
#pragma unroll
        for (int dx = 0; dx < 3; dx++) {
            int yy = y + 1 - dy, xx = x + 1 - dx;
            if (yy >= 0 && yy < HH && xx >= 0 && xx < WW) {
                size_t off = ((size_t)(b * HWp + yy * WW + xx)) * KK + (dy * 3 + dx) * DD + d;
                acl += __half2float(agg0[off]) + __half2float(agg1[off]);
            }
        }
    }
    float m = mask[pix];
    float gv = g[(size_t)pix * DD + d];
    float bgv = gv * m;
    float ACL = bgv + (acl / 9.f) * (1.f - m);
    con1[w][d] = gv;
    con1[w][64 + d] = ACL;
    __syncthreads();
    float accv = b2[d];
#pragma unroll 8
    for (int k = 0; k < 128; k++) accv = fmaf(con1[w][k], W2[k * 64 + d], accv);
    out[(size_t)pix * DD + d] = accv > 0.f ? accv : expm1f(accv);
}

extern "C" void kernel_launch(void* const* d_in, const int* in_sizes, int n_in,
                              void* d_out, int out_size, void* d_ws, size_t ws_size,
                              hipStream_t stream) {
    const float* g    = (const float*)d_in[0];
    const float* mask = (const float*)d_in[1];
    const float* W2   = (const float*)d_in[2];
    const float* b2   = (const float*)d_in[3];
    float* out = (float*)d_out;
    char* ws = (char*)d_ws;

    ushort* p1h  = (ushort*)(ws + OFFB_P1H);
    ushort* p2h  = (ushort*)(ws + OFFB_P2H);
    ushort* p1t  = (ushort*)(ws + OFFB_P1T);
    float*  k1d  = (float*) (ws + OFFB_K1D);
    void*   S    = (void*)  (ws + OFFB_S);     // fp16 CS, then bf16 CA in place
    __half* agg0 = (__half*)(ws + OFFB_AGG0);
    __half* agg1 = (__half*)(ws + OFFB_AGG1);

    build_p2<<<BB * HWp / 4, 256, 0, stream>>>(g, p2h);
    build_p1<<<BB * CC / 4, 256, 0, stream>>>(g, mask, p1h, k1d);
    transpose_p1<<<dim3(34, 9, BB), 256, 0, stream>>>(p1h, p1t);

    gemm1_nt<<<dim3(17, 18, BB), 256, 0, stream>>>(p2h, p1h, (__half*)S);

    rowsoft<<<BB * HWp, 256, 0, stream>>>(S, k1d);

    gemm2_split<<<dim3(3, 18, BB * 2), 256, 0, stream>>>((const ushort*)S, p1t, agg0, agg1);

    final_k<<<BB * HWp / 4, 256, 0, stream>>>(g, mask, agg0, agg1, W2, b2, out);
}

// Round 6
// 194.531 us; speedup vs baseline: 5.7143x; 1.0730x over previous
//
#include <hip/hip_runtime.h>
#include <hip/hip_fp16.h>
#include <math.h>

// Problem constants
#define BB 4
#define HH 48
#define WW 48
#define DD 64
#define CH 46
#define CWp 46
#define CC (CH*CWp)      // 2116
#define KK 576           // 9*64
#define HWp (HH*WW)      // 2304
#define KPAD 2176        // 34*64: row stride of S & CA, padded K for GEMM2
#define KSPLIT0 1088     // 17*64; chunk1 = [1088,2176) = 17 iters

typedef __attribute__((ext_vector_type(8))) short short8;
typedef __attribute__((ext_vector_type(4))) float float4v;

// ---------- workspace layout (byte offsets, all 16B-aligned) ----------
#define OFFB_P1H  ((size_t)0)              // bf16 [B][CC][576]       9,750,528 B
#define OFFB_P2H  ((size_t)9750528)        // bf16 [B][HW][576]      10,616,832 B
#define OFFB_P1T  ((size_t)20367360)       // bf16 [B][576][KPAD]    10,027,008 B
#define OFFB_K1D  ((size_t)30394368)       // fp32 [B][CC]               33,856 B
#define OFFB_S    ((size_t)30428224)       // fp16 CS -> bf16 CA [B][HW][KPAD] 40,108,032 B
#define OFFB_AGG0 ((size_t)70536256)       // fp16 [B][HW][576]      10,616,832 B
#define OFFB_AGG1 ((size_t)81153088)       // fp16 [B][HW][576]      10,616,832 B
// total 91,769,920 B

// ---------- helpers ----------
__device__ __forceinline__ ushort f2bf(float x) {
    unsigned u = __float_as_uint(x);
    return (ushort)((u + 0x7FFFu + ((u >> 16) & 1u)) >> 16);
}

__device__ __forceinline__ float waveReduceSum(float x) {
#pragma unroll
    for (int o = 32; o > 0; o >>= 1) x += __shfl_down(x, o, 64);
    return x;
}

__device__ __forceinline__ float blockReduceSum(float x, float* sm) {
#pragma unroll
    for (int o = 32; o > 0; o >>= 1) x += __shfl_down(x, o, 64);
    int lane = threadIdx.x & 63, w = threadIdx.x >> 6;
    __syncthreads();
    if (lane == 0) sm[w] = x;
    __syncthreads();
    return sm[0] + sm[1] + sm[2] + sm[3];
}

// fast tanh via hardware exp: tanh(z) = 1 - 2/(e^{2z}+1)
__device__ __forceinline__ float fast_tanh(float z) {
    float e = __expf(2.f * z);
    return 1.f - 2.f / (e + 1.f);
}

// async 16B global->LDS (wave-uniform LDS base + lane*16)
typedef __attribute__((address_space(3))) void lds_void_t;
typedef __attribute__((address_space(1))) void gmem_void_t;
__device__ __forceinline__ void gld16(const ushort* g, ushort* lds) {
    __builtin_amdgcn_global_load_lds((gmem_void_t*)g, (lds_void_t*)lds, 16, 0, 0);
}

// ---------- prep kernels (256 thr = 4 pixels/block, one wave each) ----------
__global__ __launch_bounds__(256) void build_p2(const float* __restrict__ g,
                                                ushort* __restrict__ p2h) {
    int pix = blockIdx.x * 4 + (threadIdx.x >> 6);
    int b = pix / HWp, yx = pix % HWp;
    int y = yx / WW, x = yx % WW;
    int c = threadIdx.x & 63;
    const float* gb = g + (size_t)b * HWp * DD;
    ushort* dst = p2h + (size_t)pix * KK;
#pragma unroll
    for (int dy = 0; dy < 3; dy++) {
#pragma unroll
        for (int dx = 0; dx < 3; dx++) {
            int yy = y + dy - 1, xx = x + dx - 1;
            float v = (yy >= 0 && yy < HH && xx >= 0 && xx < WW)
                          ? gb[((size_t)yy * WW + xx) * DD + c] : 0.f;
            dst[(dy * 3 + dx) * DD + c] = f2bf(v);
        }
    }
}

__global__ __launch_bounds__(256) void build_p1(const float* __restrict__ g,
                                                const float* __restrict__ mask,
                                                ushort* __restrict__ p1h,
                                                float* __restrict__ k1d) {
    int j = blockIdx.x * 4 + (threadIdx.x >> 6);
    int b = j / CC, jj = j % CC;
    int jy = jj / CWp, jx = jj % CWp;
    int c = threadIdx.x & 63;
    const float* gb = g + (size_t)b * HWp * DD;
    const float* mb = mask + (size_t)b * HWp;
    ushort* dst = p1h + (size_t)j * KK;
    float ss = 0.f;
#pragma unroll
    for (int dy = 0; dy < 3; dy++) {
#pragma unroll
        for (int dx = 0; dx < 3; dx++) {
            int p = (jy + dy) * WW + (jx + dx);
            float v = gb[(size_t)p * DD + c] * mb[p];
            dst[(dy * 3 + dx) * DD + c] = f2bf(v);
            ss += v * v;
        }
    }
    ss = waveReduceSum(ss);
    if (c == 0) k1d[j] = ss;
}

// p1t[b, c(576), j(KPAD)] = p1h[b, j, c], zero-filled for j >= CC
__global__ __launch_bounds__(256) void transpose_p1(const ushort* __restrict__ p1h,
                                                    ushort* __restrict__ p1t) {
    __shared__ ushort T[64 * 65];
    int b = blockIdx.z;
    int j0 = blockIdx.x * 64;   // 34 tiles * 64 = 2176 = KPAD
    int c0 = blockIdx.y * 64;
    const ushort* src = p1h + (size_t)b * CC * KK;
    ushort* dst = p1t + (size_t)b * KK * KPAD;
    int t = threadIdx.x;
#pragma unroll
    for (int pass = 0; pass < 2; pass++) {
        int v = t + pass * 256;
        int r = v >> 3, c8 = (v & 7) * 8;
        int j = j0 + r;
        uint4 d = make_uint4(0, 0, 0, 0);
        if (j < CC) d = *(const uint4*)(src + (size_t)j * KK + c0 + c8);
        ushort tmp[8];
        *(uint4*)tmp = d;
#pragma unroll
        for (int u = 0; u < 8; u++) T[r * 65 + c8 + u] = tmp[u];
    }
    __syncthreads();
#pragma unroll
    for (int pass = 0; pass < 2; pass++) {
        int v = t + pass * 256;
        int cr = v >> 3, j8 = (v & 7) * 8;
        ushort tmp[8];
#pragma unroll
        for (int u = 0; u < 8; u++) tmp[u] = T[(j8 + u) * 65 + cr];
        *(uint4*)(dst + (size_t)(c0 + cr) * KPAD + j0 + j8) = *(uint4*)tmp;
    }
}

// ---------- shared MFMA GEMM core (NT layout), BK=64, async-staged, 3-bit XOR swizzle ----------
// LDS rows of 64 ushort (8 x 16B chunks). LDS[r][p] holds global chunk p ^ (r&7).
// Store: lane l of a gld16 group writes pos l&7 of group-row l>>3, so it fetches
// global chunk (l&7)^((l>>3)&7). Read of chunk c=h*4+quad uses pos c^(l15&7):
// each 8-lane phase covers all 8 positions exactly once -> conflict-free.
template <int NBI, bool NMASK>
__device__ __forceinline__ void gemm_tile64(const ushort* __restrict__ Ab,   // += m0*lda
                                            const ushort* __restrict__ Bb,   // += n0*ldb
                                            int lda, int ldb, int kb, int ke,
                                            int Nrem,
                                            ushort* As, ushort* Bs,
                                            float4v (&acc)[4][NBI]) {
    int tid = threadIdx.x;
    int l = tid & 63, w = tid >> 6;
    int quad = l >> 4, l15 = l & 15;
    int sw = l15 & 7;                        // 3-bit read swizzle (= row&7)
    int wm = (w >> 1) * 64, wn = (w & 1) * (NBI * 16);
    int sr = l >> 3;                         // row within 8-row staging group
    int gch = (l & 7) ^ (sr & 7);            // swizzled global source chunk

    for (int k0 = kb; k0 < ke; k0 += 64) {
#pragma unroll
        for (int i = 0; i < 4; i++) {
            int rg = 4 * w + i;
            int r = rg * 8 + sr;
            gld16(Ab + (size_t)r * lda + k0 + gch * 8, As + rg * 512);
        }
#pragma unroll
        for (int i = 0; i < NBI; i++) {
            int rg = NBI * w + i;
            int r = rg * 8 + sr;
            if (!NMASK || r < Nrem)
                gld16(Bb + (size_t)r * ldb + k0 + gch * 8, Bs + rg * 512);
        }
        __syncthreads();   // compiler drains vmcnt before barrier

#pragma unroll
        for (int h = 0; h < 2; h++) {
            short8 af[4], bf[NBI];
#pragma unroll
            for (int i = 0; i < 4; i++)
                af[i] = *(const short8*)&As[(wm + i * 16 + l15) * 64 + ((h * 4 + quad) ^ sw) * 8];
#pragma unroll
            for (int j = 0; j < NBI; j++)
                bf[j] = *(const short8*)&Bs[(wn + j * 16 + l15) * 64 + ((h * 4 + quad) ^ sw) * 8];
#pragma unroll
            for (int i = 0; i < 4; i++)
#pragma unroll
                for (int j = 0; j < NBI; j++)
                    acc[i][j] = __builtin_amdgcn_mfma_f32_16x16x32_bf16(af[i], bf[j], acc[i][j], 0, 0, 0);
        }
        __syncthreads();
    }
}

// ---------- GEMM1: S[m][n] = sum_k p2h[m][k]*p1h[n][k], fp16 out, 128x128 tiles ----------
// Flat 1224-block grid; batch = XCD-pair (blkid&7)>>1 so each batch's ~5 MB
// working set stays in one XCD-pair's 8 MB of L2 (dispatch ~round-robin % 8).
__global__ __launch_bounds__(256) void gemm1_nt(const ushort* __restrict__ A,
                                                const ushort* __restrict__ Bt,
                                                __half* __restrict__ Cout) {
    __shared__ ushort As[128 * 64];
    __shared__ ushort Bs[128 * 64];
    int i0 = blockIdx.x;
    int b = (i0 & 7) >> 1;
    int tile = ((i0 >> 3) << 1) | (i0 & 1);   // 0..305, bijective over 4*306
    int ty = tile / 17, tx = tile - ty * 17;  // 18 m-tiles x 17 n-tiles
    int m0 = ty * 128, n0 = tx * 128;
    const ushort* Ab = A + (size_t)b * HWp * KK + (size_t)m0 * KK;
    const ushort* Bb = Bt + (size_t)b * CC * KK + (size_t)n0 * KK;
    float4v acc[4][4];
#pragma unroll
    for (int i = 0; i < 4; i++)
#pragma unroll
        for (int j = 0; j < 4; j++) acc[i][j] = (float4v){0.f, 0.f, 0.f, 0.f};

    gemm_tile64<4, true>(Ab, Bb, KK, KK, 0, KK, CC - n0, As, Bs, acc);

    int tid = threadIdx.x;
    int lane = tid & 63, wid = tid >> 6;
    int quad = lane >> 4, l15 = lane & 15;
    int wm = (wid >> 1) * 64, wn = (wid & 1) * 64;
    __half* C = Cout + (size_t)b * HWp * KPAD;
#pragma unroll
    for (int i = 0; i < 4; i++) {
#pragma unroll
        for (int j = 0; j < 4; j++) {
            int n = n0 + wn + j * 16 + l15;
            if (n < CC) {
#pragma unroll
                for (int r = 0; r < 4; r++) {
                    int m = m0 + wm + i * 16 + quad * 4 + r;
                    C[(size_t)m * KPAD + n] = __float2half(acc[i][j][r]);
                }
            }
        }
    }
}

// ---------- GEMM2 split-K: agg{0,1}[m][n] = sum_{k chunk} CA[m][k]*p1t[n][k] ----------
// 128m x 192n tiles, fp16 partials. Flat 432-block grid; z-slice = blkid&7
// pins each (batch,split) to one XCD for L2 locality.
__global__ __launch_bounds__(256) void gemm2_split(const ushort* __restrict__ A,
                                                   const ushort* __restrict__ Bt,
                                                   __half* __restrict__ agg0,
                                                   __half* __restrict__ agg1) {
    __shared__ ushort As[128 * 64];
    __shared__ ushort Bs[192 * 64];
    int i0 = blockIdx.x;
    int z = i0 & 7;
    int b = z >> 1, split = z & 1;
    int tile = i0 >> 3;                      // 0..53
    int ty = tile / 3, tx = tile - ty * 3;   // 18 m-tiles x 3 n-tiles
    int m0 = ty * 128, n0 = tx * 192;
    const ushort* Ab = A + (size_t)b * HWp * KPAD + (size_t)m0 * KPAD;
    const ushort* Bb = Bt + (size_t)b * KK * KPAD + (size_t)n0 * KPAD;
    float4v acc[4][6];
#pragma unroll
    for (int i = 0; i < 4; i++)
#pragma unroll
        for (int j = 0; j < 6; j++) acc[i][j] = (float4v){0.f, 0.f, 0.f, 0.f};

    gemm_tile64<6, false>(Ab, Bb, KPAD, KPAD, split ? KSPLIT0 : 0,
                          split ? KPAD : KSPLIT0, 192, As, Bs, acc);

    int tid = threadIdx.x;
    int lane = tid & 63, wid = tid >> 6;
    int quad = lane >> 4, l15 = lane & 15;
    int wm = (wid >> 1) * 64, wn = (wid & 1) * 96;
    __half* C = (split ? agg1 : agg0) + (size_t)b * HWp * KK;
#pragma unroll
    for (int i = 0; i < 4; i++) {
#pragma unroll
        for (int j = 0; j < 6; j++) {
            int n = n0 + wn + j * 16 + l15;
#pragma unroll
            for (int r = 0; r < 4; r++) {
                int m = m0 + wm + i * 16 + quad * 4 + r;
                C[(size_t)m * KK + n] = __float2half(acc[i][j][r]);
            }
        }
    }
}

// ---------- row-wise: DS1 = k1d[n]-2*CS; standardize; -50*tanh; softmax; bf16 CA ----------
__global__ __launch_bounds__(256) void rowsoft(void* __restrict__ Sbase,
                                               const float* __restrict__ k1d) {
    __shared__ float sm[4];
    size_t row = blockIdx.x;
    int b = (int)(row / HWp);
    const __half* p = (const __half*)Sbase + row * KPAD;
    ushort* wout = (ushort*)Sbase + row * KPAD;
    const float* k1 = k1d + (size_t)b * CC;
    int tid = threadIdx.x;
    float v[9];
#pragma unroll
    for (int i = 0; i < 9; i++) {
        int idx = tid + i * 256;
        v[i] = (idx < CC) ? (k1[idx] - 2.f * __half2float(p[idx])) : 0.f;
    }
    float s = 0.f;
#pragma unroll
    for (int i = 0; i < 9; i++) { int idx = tid + i * 256; if (idx < CC) s += v[i]; }
    s = blockReduceSum(s, sm);
    float mu = s / (float)CC;
    float vs = 0.f;
#pragma unroll
    for (int i = 0; i < 9; i++) {
        int idx = tid + i * 256;
        if (idx < CC) { float d = v[i] - mu; vs += d * d; }
    }
    vs = blockReduceSum(vs, sm);
    float inv_sd = 1.f / sqrtf(vs / (float)CC);
    // logits bounded in [-50,50]: exp without max-subtraction cannot overflow fp32
    float es = 0.f;
#pragma unroll
    for (int i = 0; i < 9; i++) {
        int idx = tid + i * 256;
        if (idx < CC) {
            v[i] = __expf(-50.f * fast_tanh((v[i] - mu) * inv_sd));
            es += v[i];
        }
    }
    es = blockReduceSum(es, sm);
    float invz = 1.f / es;
#pragma unroll
    for (int i = 0; i < 9; i++) {
        int idx = tid + i * 256;
        if (idx < KPAD) wout[idx] = (idx < CC) ? f2bf(v[i] * invz) : (ushort)0;
    }
}

// ---------- final: sum split partials, 9-shift combine, ACL, concat, W2, ELU ----------
__global__ __launch_bounds__(256) void final_k(const float* __restrict__ g,
                                               const float* __restrict__ mask,
                                               const __half* __restrict__ agg0,
                                               const __half* __restrict__ agg1,
                                               const float* __restrict__ W2,
                                               const float* __restrict__ b2,
                                               float* __restrict__ out) {
    int w = threadIdx.x >> 6, d = threadIdx.x & 63;
    int pix = blockIdx.x * 4 + w;
    int b = pix / HWp, yx = pix % HWp;
    int y = yx / WW, x = yx % WW;

    __shared__ float con1[4][128];
    float acl = 0.f;
#pragma unroll
    for (int dy = 0; dy < 3; dy++) {
#pragma unroll
        for (int dx = 0; dx < 3; dx++) {
            int yy = y + 1 - dy, xx = x + 1 - dx;
            if (yy >= 0 && yy < HH && xx >= 0 && xx < WW) {
                size_t off = ((size_t)(b * HWp + yy * WW + xx)) * KK + (dy * 3 + dx) * DD + d;
                acl += __half2float(agg0[off]) + __half2float(agg1[off]);
            }
        }
    }
    float m = mask[pix];
    float gv = g[(size_t)pix * DD + d];
    float bgv = gv * m;
    float ACL = bgv + (acl / 9.f) * (1.f - m);
    con1[w][d] = gv;
    con1[w][64 + d] = ACL;
    __syncthreads();
    float accv = b2[d];
#pragma unroll 8
    for (int k = 0; k < 128; k++) accv = fmaf(con1[w][k], W2[k * 64 + d], accv);
    out[(size_t)pix * DD + d] = accv > 0.f ? accv : expm1f(accv);
}

extern "C" void kernel_launch(void* const* d_in, const int* in_sizes, int n_in,
                              void* d_out, int out_size, void* d_ws, size_t ws_size,
                              hipStream_t stream) {
    const float* g    = (const float*)d_in[0];
    const float* mask = (const float*)d_in[1];
    const float* W2   = (const float*)d_in[2];
    const float* b2   = (const float*)d_in[3];
    float* out = (float*)d_out;
    char* ws = (char*)d_ws;

    ushort* p1h  = (ushort*)(ws + OFFB_P1H);
    ushort* p2h  = (ushort*)(ws + OFFB_P2H);
    ushort* p1t  = (ushort*)(ws + OFFB_P1T);
    float*  k1d  = (float*) (ws + OFFB_K1D);
    void*   S    = (void*)  (ws + OFFB_S);     // fp16 CS, then bf16 CA in place
    __half* agg0 = (__half*)(ws + OFFB_AGG0);
    __half* agg1 = (__half*)(ws + OFFB_AGG1);

    build_p2<<<BB * HWp / 4, 256, 0, stream>>>(g, p2h);
    build_p1<<<BB * CC / 4, 256, 0, stream>>>(g, mask, p1h, k1d);
    transpose_p1<<<dim3(34, 9, BB), 256, 0, stream>>>(p1h, p1t);

    gemm1_nt<<<dim3(1224), 256, 0, stream>>>(p2h, p1h, (__half*)S);

    rowsoft<<<BB * HWp, 256, 0, stream>>>(S, k1d);

    gemm2_split<<<dim3(432), 256, 0, stream>>>((const ushort*)S, p1t, agg0, agg1);

    final_k<<<BB * HWp / 4, 256, 0, stream>>>(g, mask, agg0, agg1, W2, b2, out);
}

// Round 7
// 192.819 us; speedup vs baseline: 5.7650x; 1.0089x over previous
//
#include <hip/hip_runtime.h>
#include <hip/hip_fp16.h>
#include <math.h>

// Problem constants
#define BB 4
#define HH 48
#define WW 48
#define DD 64
#define CH 46
#define CWp 46
#define CC (CH*CWp)      // 2116
#define KK 576           // 9*64
#define HWp (HH*WW)      // 2304
#define KPAD 2176        // 68*32: row stride of S & CA, padded K for GEMM2
#define KSPLIT0 1088     // 34*32; chunk1 = [1088,2176) = 34 iters

typedef __attribute__((ext_vector_type(8))) short short8;
typedef __attribute__((ext_vector_type(4))) float float4v;

// ---------- workspace layout (byte offsets, all 16B-aligned) ----------
#define OFFB_P1H  ((size_t)0)              // bf16 [B][CC][576]       9,750,528 B
#define OFFB_P2H  ((size_t)9750528)        // bf16 [B][HW][576]      10,616,832 B
#define OFFB_P1T  ((size_t)20367360)       // bf16 [B][576][KPAD]    10,027,008 B
#define OFFB_K1D  ((size_t)30394368)       // fp32 [B][CC]               33,856 B
#define OFFB_S    ((size_t)30428224)       // fp16 CS -> bf16 CA [B][HW][KPAD] 40,108,032 B
#define OFFB_AGG0 ((size_t)70536256)       // fp16 [B][HW][576]      10,616,832 B
#define OFFB_AGG1 ((size_t)81153088)       // fp16 [B][HW][576]      10,616,832 B
// total 91,769,920 B

// ---------- helpers ----------
__device__ __forceinline__ ushort f2bf(float x) {
    unsigned u = __float_as_uint(x);
    return (ushort)((u + 0x7FFFu + ((u >> 16) & 1u)) >> 16);
}

__device__ __forceinline__ float waveReduceSum(float x) {
#pragma unroll
    for (int o = 32; o > 0; o >>= 1) x += __shfl_down(x, o, 64);
    return x;
}

__device__ __forceinline__ float blockReduceSum(float x, float* sm) {
#pragma unroll
    for (int o = 32; o > 0; o >>= 1) x += __shfl_down(x, o, 64);
    int lane = threadIdx.x & 63, w = threadIdx.x >> 6;
    __syncthreads();
    if (lane == 0) sm[w] = x;
    __syncthreads();
    return sm[0] + sm[1] + sm[2] + sm[3];
}

// fast tanh via hardware exp: tanh(z) = 1 - 2/(e^{2z}+1)
__device__ __forceinline__ float fast_tanh(float z) {
    float e = __expf(2.f * z);
    return 1.f - 2.f / (e + 1.f);
}

// async 16B global->LDS (wave-uniform LDS base + lane*16)
typedef __attribute__((address_space(3))) void lds_void_t;
typedef __attribute__((address_space(1))) void gmem_void_t;
__device__ __forceinline__ void gld16(const ushort* g, ushort* lds) {
    __builtin_amdgcn_global_load_lds((gmem_void_t*)g, (lds_void_t*)lds, 16, 0, 0);
}

// ---------- fused prep: blocks [0,2304) build p2h; [2304,4420) build p1h+k1d ----------
__global__ __launch_bounds__(256) void build_patches(const float* __restrict__ g,
                                                     const float* __restrict__ mask,
                                                     ushort* __restrict__ p2h,
                                                     ushort* __restrict__ p1h,
                                                     float* __restrict__ k1d) {
    int w = threadIdx.x >> 6, c = threadIdx.x & 63;
    if (blockIdx.x < (BB * HWp / 4)) {
        int pix = blockIdx.x * 4 + w;
        int b = pix / HWp, yx = pix % HWp;
        int y = yx / WW, x = yx % WW;
        const float* gb = g + (size_t)b * HWp * DD;
        ushort* dst = p2h + (size_t)pix * KK;
#pragma unroll
        for (int dy = 0; dy < 3; dy++) {
#pragma unroll
            for (int dx = 0; dx < 3; dx++) {
                int yy = y + dy - 1, xx = x + dx - 1;
                float v = (yy >= 0 && yy < HH && xx >= 0 && xx < WW)
                              ? gb[((size_t)yy * WW + xx) * DD + c] : 0.f;
                dst[(dy * 3 + dx) * DD + c] = f2bf(v);
            }
        }
    } else {
        int j = (blockIdx.x - BB * HWp / 4) * 4 + w;
        int b = j / CC, jj = j % CC;
        int jy = jj / CWp, jx = jj % CWp;
        const float* gb = g + (size_t)b * HWp * DD;
        const float* mb = mask + (size_t)b * HWp;
        ushort* dst = p1h + (size_t)j * KK;
        float ss = 0.f;
#pragma unroll
        for (int dy = 0; dy < 3; dy++) {
#pragma unroll
            for (int dx = 0; dx < 3; dx++) {
                int p = (jy + dy) * WW + (jx + dx);
                float v = gb[(size_t)p * DD + c] * mb[p];
                dst[(dy * 3 + dx) * DD + c] = f2bf(v);
                ss += v * v;
            }
        }
        ss = waveReduceSum(ss);
        if (c == 0) k1d[j] = ss;
    }
}

// p1t[b, c(576), j(KPAD)] = p1h[b, j, c], zero-filled for j >= CC
__global__ __launch_bounds__(256) void transpose_p1(const ushort* __restrict__ p1h,
                                                    ushort* __restrict__ p1t) {
    __shared__ ushort T[64 * 65];
    int b = blockIdx.z;
    int j0 = blockIdx.x * 64;   // 34 tiles * 64 = 2176 = KPAD
    int c0 = blockIdx.y * 64;
    const ushort* src = p1h + (size_t)b * CC * KK;
    ushort* dst = p1t + (size_t)b * KK * KPAD;
    int t = threadIdx.x;
#pragma unroll
    for (int pass = 0; pass < 2; pass++) {
        int v = t + pass * 256;
        int r = v >> 3, c8 = (v & 7) * 8;
        int j = j0 + r;
        uint4 d = make_uint4(0, 0, 0, 0);
        if (j < CC) d = *(const uint4*)(src + (size_t)j * KK + c0 + c8);
        ushort tmp[8];
        *(uint4*)tmp = d;
#pragma unroll
        for (int u = 0; u < 8; u++) T[r * 65 + c8 + u] = tmp[u];
    }
    __syncthreads();
#pragma unroll
    for (int pass = 0; pass < 2; pass++) {
        int v = t + pass * 256;
        int cr = v >> 3, j8 = (v & 7) * 8;
        ushort tmp[8];
#pragma unroll
        for (int u = 0; u < 8; u++) tmp[u] = T[(j8 + u) * 65 + cr];
        *(uint4*)(dst + (size_t)(c0 + cr) * KPAD + j0 + j8) = *(uint4*)tmp;
    }
}

// ---------- MFMA GEMM core (NT), BK=32, DOUBLE-BUFFERED, single barrier/iter ----------
// LDS rows of 32 ushort (4 x 16B chunks), R4's verified zero-conflict swizzle:
// LDS[r][pos] = global chunk pos ^ ((r>>1)&3); read chunk quad uses pos quad^((l15>>1)&3).
// Loop: barrier (drains prefetch issued one MFMA-phase ago) -> prefetch next into
// buf^1 -> MFMA from buf. One barrier per K-iteration.
// NF = n-frags per wave (4 -> 128-wide B tile, 6 -> 192); B staging insts = NF/2.
template <int NF, bool NMASK>
__device__ __forceinline__ void gemm_tile_db(const ushort* __restrict__ Ab,   // += m0*lda
                                             const ushort* __restrict__ Bb,   // += n0*ldb
                                             int lda, int ldb, int kb, int ke,
                                             int Nrem,
                                             ushort* As, ushort* Bs,
                                             float4v (&acc)[4][NF]) {
    constexpr int NBI = NF / 2;
    constexpr int BBUF = 2048 * NBI;          // ushorts per B buffer
    int tid = threadIdx.x;
    int l = tid & 63, w = tid >> 6;
    int quad = l >> 4, l15 = l & 15;
    int sw8 = (l15 >> 1) & 3;
    int wm = (w >> 1) * 64, wn = (w & 1) * (NF * 16);
    int rowInC = l >> 2;                      // 0..15 within 16-row chunk
    int cSw = (l & 3) ^ ((l >> 3) & 3);       // swizzled global source chunk

    // prologue: stage k=kb into buffer 0
#pragma unroll
    for (int i = 0; i < 2; i++) {
        int rg = w * 2 + i;
        gld16(Ab + (size_t)(rg * 16 + rowInC) * lda + kb + cSw * 8, As + rg * 512);
    }
#pragma unroll
    for (int i = 0; i < NBI; i++) {
        int rg = w * NBI + i;
        int r = rg * 16 + rowInC;
        if (!NMASK || r < Nrem)
            gld16(Bb + (size_t)r * ldb + kb + cSw * 8, Bs + rg * 512);
    }

    int buf = 0;
    for (int k0 = kb; k0 < ke; k0 += 32) {
        __syncthreads();   // vmcnt drain: buf's loads ready; lgkm: prev reads done
        int nb = buf ^ 1;
        if (k0 + 32 < ke) {
#pragma unroll
            for (int i = 0; i < 2; i++) {
                int rg = w * 2 + i;
                gld16(Ab + (size_t)(rg * 16 + rowInC) * lda + (k0 + 32) + cSw * 8,
                      As + nb * 4096 + rg * 512);
            }
#pragma unroll
            for (int i = 0; i < NBI; i++) {
                int rg = w * NBI + i;
                int r = rg * 16 + rowInC;
                if (!NMASK || r < Nrem)
                    gld16(Bb + (size_t)r * ldb + (k0 + 32) + cSw * 8,
                          Bs + nb * BBUF + rg * 512);
            }
        }
        const ushort* Ax = As + buf * 4096;
        const ushort* Bx = Bs + buf * BBUF;
        short8 af[4], bf[NF];
#pragma unroll
        for (int i = 0; i < 4; i++)
            af[i] = *(const short8*)&Ax[(wm + i * 16 + l15) * 32 + ((quad ^ sw8)) * 8];
#pragma unroll
        for (int j = 0; j < NF; j++)
            bf[j] = *(const short8*)&Bx[(wn + j * 16 + l15) * 32 + ((quad ^ sw8)) * 8];
#pragma unroll
        for (int i = 0; i < 4; i++)
#pragma unroll
            for (int j = 0; j < NF; j++)
                acc[i][j] = __builtin_amdgcn_mfma_f32_16x16x32_bf16(af[i], bf[j], acc[i][j], 0, 0, 0);
        buf = nb;
    }
}

// ---------- GEMM1: S[m][n] = sum_k p2h[m][k]*p1h[n][k], fp16 out, 128x128 tiles ----------
// Flat 1224-block grid; batch = XCD-pair (blkid&7)>>1 (L2 locality heuristic).
__global__ __launch_bounds__(256) void gemm1_nt(const ushort* __restrict__ A,
                                                const ushort* __restrict__ Bt,
                                                __half* __restrict__ Cout) {
    __shared__ ushort As[2 * 4096];
    __shared__ ushort Bs[2 * 4096];
    int i0 = blockIdx.x;
    int b = (i0 & 7) >> 1;
    int tile = ((i0 >> 3) << 1) | (i0 & 1);   // 0..305, bijective over 4*306
    int ty = tile / 17, tx = tile - ty * 17;  // 18 m-tiles x 17 n-tiles
    int m0 = ty * 128, n0 = tx * 128;
    const ushort* Ab = A + (size_t)b * HWp * KK + (size_t)m0 * KK;
    const ushort* Bb = Bt + (size_t)b * CC * KK + (size_t)n0 * KK;
    float4v acc[4][4];
#pragma unroll
    for (int i = 0; i < 4; i++)
#pragma unroll
        for (int j = 0; j < 4; j++) acc[i][j] = (float4v){0.f, 0.f, 0.f, 0.f};

    gemm_tile_db<4, true>(Ab, Bb, KK, KK, 0, KK, CC - n0, As, Bs, acc);

    int tid = threadIdx.x;
    int lane = tid & 63, wid = tid >> 6;
    int quad = lane >> 4, l15 = lane & 15;
    int wm = (wid >> 1) * 64, wn = (wid & 1) * 64;
    __half* C = Cout + (size_t)b * HWp * KPAD;
#pragma unroll
    for (int i = 0; i < 4; i++) {
#pragma unroll
        for (int j = 0; j < 4; j++) {
            int n = n0 + wn + j * 16 + l15;
            if (n < CC) {
#pragma unroll
                for (int r = 0; r < 4; r++) {
                    int m = m0 + wm + i * 16 + quad * 4 + r;
                    C[(size_t)m * KPAD + n] = __float2half(acc[i][j][r]);
                }
            }
        }
    }
}

// ---------- GEMM2 split-K: agg{0,1}[m][n] = sum_{k chunk} CA[m][k]*p1t[n][k] ----------
// 128m x 192n tiles, fp16 partials. Flat 432-block grid; z-slice = blkid&7.
__global__ __launch_bounds__(256) void gemm2_split(const ushort* __restrict__ A,
                                                   const ushort* __restrict__ Bt,
                                                   __half* __restrict__ agg0,
                                                   __half* __restrict__ agg1) {
    __shared__ ushort As[2 * 4096];
    __shared__ ushort Bs[2 * 6144];
    int i0 = blockIdx.x;
    int z = i0 & 7;
    int b = z >> 1, split = z & 1;
    int tile = i0 >> 3;                      // 0..53
    int ty = tile / 3, tx = tile - ty * 3;   // 18 m-tiles x 3 n-tiles
    int m0 = ty * 128, n0 = tx * 192;
    const ushort* Ab = A + (size_t)b * HWp * KPAD + (size_t)m0 * KPAD;
    const ushort* Bb = Bt + (size_t)b * KK * KPAD + (size_t)n0 * KPAD;
    float4v acc[4][6];
#pragma unroll
    for (int i = 0; i < 4; i++)
#pragma unroll
        for (int j = 0; j < 6; j++) acc[i][j] = (float4v){0.f, 0.f, 0.f, 0.f};

    gemm_tile_db<6, false>(Ab, Bb, KPAD, KPAD, split ? KSPLIT0 : 0,
                           split ? KPAD : KSPLIT0, 192, As, Bs, acc);

    int tid = threadIdx.x;
    int lane = tid & 63, wid = tid >> 6;
    int quad = lane >> 4, l15 = lane & 15;
    int wm = (wid >> 1) * 64, wn = (wid & 1) * 96;
    __half* C = (split ? agg1 : agg0) + (size_t)b * HWp * KK;
#pragma unroll
    for (int i = 0; i < 4; i++) {
#pragma unroll
        for (int j = 0; j < 6; j++) {
            int n = n0 + wn + j * 16 + l15;
#pragma unroll
            for (int r = 0; r < 4; r++) {
                int m = m0 + wm + i * 16 + quad * 4 + r;
                C[(size_t)m * KK + n] = __float2half(acc[i][j][r]);
            }
        }
    }
}

// ---------- row-wise: DS1 = k1d[n]-2*CS; standardize; -50*tanh; softmax; bf16 CA ----------
// Vectorized: thread t owns halves [8t,8t+8) (t<256 covers 2048) plus, for t<34,
// the remainder pair [2048+2t, 2048+2t+2) (covers 2048..2115 = CC).
__global__ __launch_bounds__(256) void rowsoft(void* __restrict__ Sbase,
                                               const float* __restrict__ k1d) {
    __shared__ float sm[4];
    size_t row = blockIdx.x;
    int b = (int)(row / HWp);
    const __half* p = (const __half*)Sbase + row * KPAD;
    ushort* wout = (ushort*)Sbase + row * KPAD;
    const float* k1 = k1d + (size_t)b * CC;
    int t = threadIdx.x;
    bool hasx = t < 34;

    uint4 raw = *(const uint4*)(p + t * 8);
    uint rx = hasx ? *(const uint*)(p + 2048 + t * 2) : 0u;
    float v[8], vx[2];
    {
        const __half2* h2 = (const __half2*)&raw;
#pragma unroll
        for (int i = 0; i < 4; i++) {
            float2 f = __half22float2(h2[i]);
            v[2 * i] = f.x; v[2 * i + 1] = f.y;
        }
        __half2 hx = *(__half2*)&rx;
        float2 fx = __half22float2(hx);
        vx[0] = fx.x; vx[1] = fx.y;
    }
    // DS1 = k1 - 2*CS
    {
        const float* kp = k1 + t * 8;
#pragma unroll
        for (int i = 0; i < 8; i++) v[i] = kp[i] - 2.f * v[i];
        if (hasx) {
            vx[0] = k1[2048 + t * 2] - 2.f * vx[0];
            vx[1] = k1[2048 + t * 2 + 1] - 2.f * vx[1];
        }
    }
    float s = 0.f;
#pragma unroll
    for (int i = 0; i < 8; i++) s += v[i];
    if (hasx) s += vx[0] + vx[1];
    s = blockReduceSum(s, sm);
    float mu = s / (float)CC;
    float vs = 0.f;
#pragma unroll
    for (int i = 0; i < 8; i++) { float d = v[i] - mu; vs += d * d; }
    if (hasx) { float d0 = vx[0] - mu, d1 = vx[1] - mu; vs += d0 * d0 + d1 * d1; }
    vs = blockReduceSum(vs, sm);
    float inv_sd = 1.f / sqrtf(vs / (float)CC);
    // logits bounded in [-50,50]: exp without max-subtraction cannot overflow fp32
    float es = 0.f;
#pragma unroll
    for (int i = 0; i < 8; i++) {
        v[i] = __expf(-50.f * fast_tanh((v[i] - mu) * inv_sd));
        es += v[i];
    }
    if (hasx) {
        vx[0] = __expf(-50.f * fast_tanh((vx[0] - mu) * inv_sd));
        vx[1] = __expf(-50.f * fast_tanh((vx[1] - mu) * inv_sd));
        es += vx[0] + vx[1];
    }
    es = blockReduceSum(es, sm);
    float invz = 1.f / es;

    ushort o[8];
#pragma unroll
    for (int i = 0; i < 8; i++) o[i] = f2bf(v[i] * invz);
    *(uint4*)(wout + t * 8) = *(const uint4*)o;
    if (hasx) {
        ushort ox[2] = { f2bf(vx[0] * invz), f2bf(vx[1] * invz) };
        *(uint*)(wout + 2048 + t * 2) = *(const uint*)ox;
    } else {
        // zero-fill pad [CC, KPAD): threads 34..63 cover 60 halves
        *(uint*)(wout + CC + 2 * (t - 34)) = 0u;
    }
}

// ---------- final: sum split partials, 9-shift combine, ACL, concat, W2, ELU ----------
__global__ __launch_bounds__(256) void final_k(const float* __restrict__ g,
                                               const float* __restrict__ mask,
                                               const __half* __restrict__ agg0,
                                               const __half* __restrict__ agg1,
                                               const float* __restrict__ W2,
                                               const float* __restrict__ b2,
                                               float* __restrict__ out) {
    int w = threadIdx.x >> 6, d = threadIdx.x & 63;
    int pix = blockIdx.x * 4 + w;
    int b = pix / HWp, yx = pix % HWp;
    int y = yx / WW, x = yx % WW;

    __shared__ float con1[4][128];
    float acl = 0.f;
#pragma unroll
    for (int dy = 0; dy < 3; dy++) {
#pragma unroll
        for (int dx = 0; dx < 3; dx++) {
            int yy = y + 1 - dy, xx = x + 1 - dx;
            if (yy >= 0 && yy < HH && xx >= 0 && xx < WW) {
                size_t off = ((size_t)(b * HWp + yy * WW + xx)) * KK + (dy * 3 + dx) * DD + d;
                acl += __half2float(agg0[off]) + __half2float(agg1[off]);
            }
        }
    }
    float m = mask[pix];
    float gv = g[(size_t)pix * DD + d];
    float bgv = gv * m;
    float ACL = bgv + (acl / 9.f) * (1.f - m);
    con1[w][d] = gv;
    con1[w][64 + d] = ACL;
    __syncthreads();
    float accv = b2[d];
#pragma unroll 8
    for (int k = 0; k < 128; k++) accv = fmaf(con1[w][k], W2[k * 64 + d], accv);
    out[(size_t)pix * DD + d] = accv > 0.f ? accv : expm1f(accv);
}

extern "C" void kernel_launch(void* const* d_in, const int* in_sizes, int n_in,
                              void* d_out, int out_size, void* d_ws, size_t ws_size,
                              hipStream_t stream) {
    const float* g    = (const float*)d_in[0];
    const float* mask = (const float*)d_in[1];
    const float* W2   = (const float*)d_in[2];
    const float* b2   = (const float*)d_in[3];
    float* out = (float*)d_out;
    char* ws = (char*)d_ws;

    ushort* p1h  = (ushort*)(ws + OFFB_P1H);
    ushort* p2h  = (ushort*)(ws + OFFB_P2H);
    ushort* p1t  = (ushort*)(ws + OFFB_P1T);
    float*  k1d  = (float*) (ws + OFFB_K1D);
    void*   S    = (void*)  (ws + OFFB_S);     // fp16 CS, then bf16 CA in place
    __half* agg0 = (__half*)(ws + OFFB_AGG0);
    __half* agg1 = (__half*)(ws + OFFB_AGG1);

    build_patches<<<BB * HWp / 4 + BB * CC / 4, 256, 0, stream>>>(g, mask, p2h, p1h, k1d);
    transpose_p1<<<dim3(34, 9, BB), 256, 0, stream>>>(p1h, p1t);

    gemm1_nt<<<dim3(1224), 256, 0, stream>>>(p2h, p1h, (__half*)S);

    rowsoft<<<BB * HWp, 256, 0, stream>>>(S, k1d);

    gemm2_split<<<dim3(432), 256, 0, stream>>>((const ushort*)S, p1t, agg0, agg1);

    final_k<<<BB * HWp / 4, 256, 0, stream>>>(g, mask, agg0, agg1, W2, b2, out);
}